// Round 5
// baseline (360.355 us; speedup 1.0000x reference)
//
#include <hip/hip_runtime.h>

#define LRELU(a) ((a) > 0.f ? (a) : 0.2f * (a))

// ---------- block-wide inclusive scan helper (256 threads, 4 waves) ----------
__device__ __forceinline__ int blockScanIncl256(int v, int* wl) {
  int t = threadIdx.x, lane = t & 63, w = t >> 6;
  int x = v;
#pragma unroll
  for (int o = 1; o < 64; o <<= 1) {
    int tmp = __shfl_up(x, (unsigned)o, 64);
    if (lane >= o) x += tmp;
  }
  if (lane == 63) wl[w] = x;
  __syncthreads();
  if (t == 0) {
    int s = 0;
#pragma unroll
    for (int j = 0; j < 4; ++j) { int tv = wl[j]; wl[j] = s; s += tv; }
  }
  __syncthreads();
  return x + wl[w];
}

// ---------- CSR build ----------
__global__ __launch_bounds__(256) void k_deg(const int* __restrict__ dst,
                                             int* __restrict__ deg, int E) {
  int e = blockIdx.x * 256 + threadIdx.x;
  if (e < E) atomicAdd(&deg[dst[e]], 1);
}

__global__ __launch_bounds__(256) void k_chunksum(const int* __restrict__ deg,
                                                  int* __restrict__ bsum, int n) {
  __shared__ int wl[4];
  int i = blockIdx.x * 256 + threadIdx.x;
  int v = (i < n) ? deg[i] : 0;
#pragma unroll
  for (int o = 1; o < 64; o <<= 1) v += __shfl_xor(v, o, 64);
  int lane = threadIdx.x & 63, w = threadIdx.x >> 6;
  if (lane == 0) wl[w] = v;
  __syncthreads();
  if (threadIdx.x == 0) bsum[blockIdx.x] = wl[0] + wl[1] + wl[2] + wl[3];
}

// single block; requires nb <= 256 (N <= 65536)
__global__ __launch_bounds__(256) void k_bscan(int* __restrict__ bsum, int nb,
                                               int* __restrict__ csr_off, int n) {
  __shared__ int wl[4];
  int t = threadIdx.x;
  int v = (t < nb) ? bsum[t] : 0;
  int incl = blockScanIncl256(v, wl);
  if (t < nb) bsum[t] = incl - v;  // exclusive block offsets
  if (t == 255) csr_off[n] = incl; // grand total
}

__global__ __launch_bounds__(256) void k_chunkscan(const int* __restrict__ deg,
                                                   const int* __restrict__ bsum,
                                                   int* __restrict__ csr_off,
                                                   int* __restrict__ fill, int n) {
  __shared__ int wl[4];
  int i = blockIdx.x * 256 + threadIdx.x;
  int v = (i < n) ? deg[i] : 0;
  int incl = blockScanIncl256(v, wl);
  int o = bsum[blockIdx.x] + incl - v;
  if (i < n) { csr_off[i] = o; fill[i] = o; }
}

// one scattered 8B write per edge: pack[p] = {edge_id, src}
__global__ __launch_bounds__(256) void k_scatter(const int* __restrict__ dst,
                                                 const int* __restrict__ src,
                                                 int* __restrict__ fill,
                                                 int2* __restrict__ pack, int E) {
  int e = blockIdx.x * 256 + threadIdx.x;
  if (e < E) {
    int d = dst[e];
    int p = atomicAdd(&fill[d], 1);
    pack[p] = make_int2(e, src[e]);
  }
}

// ---------- tiled f32 GEMM + fused attention-logit epilogue ----------
// H[b0:b0+64][0:64] = X[b0:b0+64][0:K] @ W[K][64]; als/ald = h . a per head.
// 256 threads = 16x16, each computes a 4x4 tile. X stride must equal K.
template <int K, int HH>
__global__ __launch_bounds__(256) void k_gemm(const float* __restrict__ X,
                                              const float* __restrict__ W,
                                              const float* __restrict__ a_s,
                                              const float* __restrict__ a_d,
                                              float* __restrict__ H,
                                              float* __restrict__ als,
                                              float* __restrict__ ald, int n) {
  __shared__ float Xs[64][K + 4];
  __shared__ float Ws[K][64];
  int t = threadIdx.x;
  int b0 = blockIdx.x * 64;
  for (int i = t; i < K * 64; i += 256) Ws[i >> 6][i & 63] = W[i];
  for (int i = t; i < 64 * K; i += 256) {
    int node = i / K, k = i % K;
    int r = b0 + node;
    Xs[node][k] = (r < n) ? X[(size_t)r * K + k] : 0.f;
  }
  __syncthreads();
  int tx = t & 15, ty = t >> 4;
  float acc[4][4] = {};
#pragma unroll 2
  for (int k4 = 0; k4 < K; k4 += 4) {
    float wvf[4][4];
#pragma unroll
    for (int j = 0; j < 4; ++j)
      *(float4*)&wvf[j][0] = *(const float4*)&Ws[k4 + j][tx * 4];
#pragma unroll
    for (int i = 0; i < 4; ++i) {
      float xvf[4];
      *(float4*)&xvf[0] = *(const float4*)&Xs[ty * 4 + i][k4];
#pragma unroll
      for (int kk = 0; kk < 4; ++kk)
#pragma unroll
        for (int j = 0; j < 4; ++j)
          acc[i][j] = fmaf(xvf[kk], wvf[kk][j], acc[i][j]);
    }
  }
#pragma unroll
  for (int i = 0; i < 4; ++i) {
    int node = b0 + ty * 4 + i;
    if (node < n)
      *(float4*)&H[(size_t)node * 64 + tx * 4] =
          make_float4(acc[i][0], acc[i][1], acc[i][2], acc[i][3]);
  }
  // ---- fused attention logits: als/ald[node*HH+head] ----
  constexpr int C = 64 / HH;     // channels per head
  constexpr int GL = C / 4;      // tx lanes per head group
  float asv[4], adv[4];
#pragma unroll
  for (int j = 0; j < 4; ++j) { asv[j] = a_s[tx * 4 + j]; adv[j] = a_d[tx * 4 + j]; }
#pragma unroll
  for (int i = 0; i < 4; ++i) {
    float ps = 0.f, pd = 0.f;
#pragma unroll
    for (int j = 0; j < 4; ++j) {
      ps = fmaf(acc[i][j], asv[j], ps);
      pd = fmaf(acc[i][j], adv[j], pd);
    }
#pragma unroll
    for (int o = 1; o < GL; o <<= 1) {
      ps += __shfl_xor(ps, o, 64);
      pd += __shfl_xor(pd, o, 64);
    }
    int node = b0 + ty * 4 + i;
    if (node < n && (tx & (GL - 1)) == 0) {
      int head = tx / GL;
      als[(size_t)node * HH + head] = ps;
      ald[(size_t)node * HH + head] = pd;
    }
  }
}

// ---------- fused edge pass (the ONLY random read of edge_attr) ----------
// wave per node, 16 lanes x 4 edges. Produces:
//   elog1[i][h]   = LRELU(als1[s]+ald1[node]+ea@wa1[:,h])   (CSR order)
//   eadot2[i]     = ea@wa2                                   (CSR order)
//   selfl1[node]  = LRELU(als1+ald1+mean_ea@wa1)
//   loopdot2[node]= mean_ea@wa2
__global__ __launch_bounds__(256) void k_edgepass(
    const int* __restrict__ csr_off, const int2* __restrict__ pack,
    const float* __restrict__ edge_attr,
    const float* __restrict__ We1, const float* __restrict__ ae1,
    const float* __restrict__ We2, const float* __restrict__ ae2,
    const float* __restrict__ als1, const float* __restrict__ ald1,
    float* __restrict__ elog1, float* __restrict__ selfl1,
    float* __restrict__ eadot2, float* __restrict__ loopdot2, int n) {
  __shared__ float wa1s[64];  // [k*4+h] = sum_c We1[k,h*16+c]*ae1[h,c]
  __shared__ float wa2s[16];  // [k]     = sum_c We2[k,c]*ae2[c]
  int t = threadIdx.x;
  if (t < 64) {
    int k = t >> 2, hh = t & 3;
    float s = 0.f;
#pragma unroll
    for (int c = 0; c < 16; ++c) s = fmaf(We1[k * 64 + hh * 16 + c], ae1[hh * 16 + c], s);
    wa1s[t] = s;
  } else if (t < 80) {
    int k = t - 64;
    float s = 0.f;
#pragma unroll
    for (int c = 0; c < 64; ++c) s = fmaf(We2[k * 64 + c], ae2[c], s);
    wa2s[k] = s;
  }
  __syncthreads();
  int w = t >> 6, lane = t & 63;
  int node = blockIdx.x * 4 + w;
  if (node >= n) return;
  int sub = lane >> 4, k = lane & 15;
  int s0 = csr_off[node], s1 = csr_off[node + 1];
  float wa1v[4];
#pragma unroll
  for (int h = 0; h < 4; ++h) wa1v[h] = wa1s[k * 4 + h];
  float wa2v = wa2s[k];
  float ad1v = ald1[(size_t)node * 4 + (lane & 3)];
  float lsum = 0.f;
  for (int i0 = s0; i0 < s1; i0 += 4) {
    int i = i0 + sub;
    bool valid = i < s1;
    int e = 0, s = 0;
    if (valid) { int2 p = pack[i]; e = p.x; s = p.y; }
    float ea = valid ? edge_attr[(size_t)e * 16 + k] : 0.f;
    lsum += ea;
    float p0 = ea * wa1v[0], p1 = ea * wa1v[1];
    float p2 = ea * wa1v[2], p3 = ea * wa1v[3];
    float q = ea * wa2v;
#pragma unroll
    for (int o = 1; o < 16; o <<= 1) {
      p0 += __shfl_xor(p0, o, 64);
      p1 += __shfl_xor(p1, o, 64);
      p2 += __shfl_xor(p2, o, 64);
      p3 += __shfl_xor(p3, o, 64);
      q  += __shfl_xor(q,  o, 64);
    }
    if (valid) {
      if (k < 4) {
        float ph = (k == 0) ? p0 : (k == 1) ? p1 : (k == 2) ? p2 : p3;
        float lg = als1[(size_t)s * 4 + k] + ad1v + ph;
        elog1[(size_t)i * 4 + k] = LRELU(lg);
      } else if (k == 4) {
        eadot2[i] = q;
      }
    }
  }
  // combine sub-groups: per-k totals
  lsum += __shfl_xor(lsum, 16, 64);
  lsum += __shfl_xor(lsum, 32, 64);
  float mean = lsum / fmaxf((float)(s1 - s0), 1.f);
  float l0 = mean * wa1v[0], l1 = mean * wa1v[1];
  float l2 = mean * wa1v[2], l3 = mean * wa1v[3];
  float lq = mean * wa2v;
#pragma unroll
  for (int o = 1; o < 16; o <<= 1) {
    l0 += __shfl_xor(l0, o, 64);
    l1 += __shfl_xor(l1, o, 64);
    l2 += __shfl_xor(l2, o, 64);
    l3 += __shfl_xor(l3, o, 64);
    lq += __shfl_xor(lq, o, 64);
  }
  if (lane < 4) {
    float ph = (lane == 0) ? l0 : (lane == 1) ? l1 : (lane == 2) ? l2 : l3;
    float lg = als1[(size_t)node * 4 + lane] + ald1[(size_t)node * 4 + lane] + ph;
    selfl1[(size_t)node * 4 + lane] = LRELU(lg);
  } else if (lane == 4) {
    loopdot2[node] = lq;
  }
}

// ---------- layer 1 aggregation ----------
// phase 1: exact segment max+denom from sequential elog reads (lanes = 16 edges x 4 heads)
// phase 2: batched (8-deep, double-buffered) h gathers, pure exp*fma accumulation
__global__ __launch_bounds__(256) void k_agg1(const int* __restrict__ csr_off,
                                              const int2* __restrict__ pack,
                                              const float* __restrict__ elog,
                                              const float* __restrict__ selfl,
                                              const float* __restrict__ h1,
                                              const float* __restrict__ b1,
                                              float* __restrict__ out1, int n) {
  int t = threadIdx.x, w = t >> 6, lane = t & 63;
  int node = blockIdx.x * 4 + w;
  if (node >= n) return;
  int s0 = csr_off[node], s1 = csr_off[node + 1];
  int nit = s1 - s0;
  // ---- phase 1 ----
  int h4 = lane & 3;
  float sl4 = selfl[node * 4 + h4];
  float m = sl4;
  for (int i = s0 + (lane >> 2); i < s1; i += 16)
    m = fmaxf(m, elog[(size_t)i * 4 + h4]);
#pragma unroll
  for (int o = 4; o < 64; o <<= 1) m = fmaxf(m, __shfl_xor(m, o, 64));
  float den = ((lane >> 2) == 0) ? __expf(sl4 - m) : 0.f;
  for (int i = s0 + (lane >> 2); i < s1; i += 16)
    den += __expf(elog[(size_t)i * 4 + h4] - m);
#pragma unroll
  for (int o = 4; o < 64; o <<= 1) den += __shfl_xor(den, o, 64);
  int head = lane >> 4;  // head in channel layout
  float m_ch = __shfl(m, head, 64);
  float rd_ch = 1.f / __shfl(den, head, 64);
  float sl_ch = __shfl(sl4, head, 64);
  float acc = __expf(sl_ch - m_ch) * h1[(size_t)node * 64 + lane];
  // ---- phase 2 ----
  if (nit > 0) {
    int nb = (nit + 7) >> 3;
    int laneE = lane & 7, laneB = (lane >> 2) & 7, laneH = lane & 3;
    int sv; float ev;
    float bufA[8], bufB[8];
    {
      int i1 = min(s0 + laneE, s1 - 1);
      sv = pack[i1].y;
      int i2 = min(s0 + laneB, s1 - 1);
      ev = elog[(size_t)i2 * 4 + laneH];
    }
#pragma unroll
    for (int j = 0; j < 8; ++j)
      bufA[j] = h1[(size_t)__shfl(sv, j, 64) * 64 + lane];
    for (int b = 0; b < nb; ++b) {
      int svN = 0; float evN = 0.f;
      bool pf = (b + 1 < nb);
      if (pf) {
        int base = s0 + (b + 1) * 8;
        int i1 = min(base + laneE, s1 - 1);
        svN = pack[i1].y;
        int i2 = min(base + laneB, s1 - 1);
        evN = elog[(size_t)i2 * 4 + laneH];
#pragma unroll
        for (int j = 0; j < 8; ++j)
          bufB[j] = h1[(size_t)__shfl(svN, j, 64) * 64 + lane];
      }
      int rem = nit - b * 8;
#pragma unroll
      for (int j = 0; j < 8; ++j) {
        float aj = __shfl(ev, j * 4 + head, 64);
        float ex = (j < rem) ? __expf(aj - m_ch) : 0.f;
        acc = fmaf(ex, bufA[j], acc);
      }
      if (pf) {
#pragma unroll
        for (int j = 0; j < 8; ++j) bufA[j] = bufB[j];
        sv = svN; ev = evN;
      }
    }
  }
  float r = acc * rd_ch + b1[lane];
  out1[(size_t)node * 64 + lane] = r > 0.f ? r : expm1f(r);  // ELU fused
}

// ---------- layer 2 logits: wave per node (dst = node), no edge_attr read ----------
__global__ __launch_bounds__(256) void k_l2log(const int* __restrict__ csr_off,
                                               const int2* __restrict__ pack,
                                               const float* __restrict__ eadot2,
                                               const float* __restrict__ loopdot2,
                                               const float* __restrict__ als2,
                                               const float* __restrict__ ald2,
                                               float* __restrict__ elog2,
                                               float* __restrict__ selfl2, int n) {
  int t = threadIdx.x, w = t >> 6, lane = t & 63;
  int node = blockIdx.x * 4 + w;
  if (node >= n) return;
  float adv = ald2[node];
  if (lane == 0) {
    float lg = als2[node] + adv + loopdot2[node];
    selfl2[node] = LRELU(lg);
  }
  int s0 = csr_off[node], s1 = csr_off[node + 1];
  for (int i = s0 + lane; i < s1; i += 64) {
    int s = pack[i].y;
    float lg = als2[s] + adv + eadot2[i];
    elog2[i] = LRELU(lg);
  }
}

// ---------- layer 2 aggregation (scalar head) ----------
__global__ __launch_bounds__(256) void k_agg2(const int* __restrict__ csr_off,
                                              const int2* __restrict__ pack,
                                              const float* __restrict__ elog,
                                              const float* __restrict__ selfl,
                                              const float* __restrict__ h2,
                                              const float* __restrict__ b2,
                                              float* __restrict__ out2, int n) {
  int t = threadIdx.x, w = t >> 6, lane = t & 63;
  int node = blockIdx.x * 4 + w;
  if (node >= n) return;
  int s0 = csr_off[node], s1 = csr_off[node + 1];
  int nit = s1 - s0;
  // ---- phase 1 ----
  float sl = selfl[node];
  float m = sl;
  for (int i = s0 + lane; i < s1; i += 64) m = fmaxf(m, elog[i]);
#pragma unroll
  for (int o = 1; o < 64; o <<= 1) m = fmaxf(m, __shfl_xor(m, o, 64));
  float den = (lane == 0) ? __expf(sl - m) : 0.f;
  for (int i = s0 + lane; i < s1; i += 64) den += __expf(elog[i] - m);
#pragma unroll
  for (int o = 1; o < 64; o <<= 1) den += __shfl_xor(den, o, 64);
  float rd = 1.f / den;
  float acc = __expf(sl - m) * h2[(size_t)node * 64 + lane];
  // ---- phase 2 ----
  if (nit > 0) {
    int nb = (nit + 7) >> 3;
    int laneE = lane & 7;
    int sv; float ev;
    {
      int i1 = min(s0 + laneE, s1 - 1);
      sv = pack[i1].y;
      ev = elog[i1];
    }
    float bufA[8], bufB[8];
#pragma unroll
    for (int j = 0; j < 8; ++j)
      bufA[j] = h2[(size_t)__shfl(sv, j, 64) * 64 + lane];
    for (int b = 0; b < nb; ++b) {
      int svN = 0; float evN = 0.f;
      bool pf = (b + 1 < nb);
      if (pf) {
        int i1 = min(s0 + (b + 1) * 8 + laneE, s1 - 1);
        svN = pack[i1].y;
        evN = elog[i1];
#pragma unroll
        for (int j = 0; j < 8; ++j)
          bufB[j] = h2[(size_t)__shfl(svN, j, 64) * 64 + lane];
      }
      int rem = nit - b * 8;
#pragma unroll
      for (int j = 0; j < 8; ++j) {
        float aj = __shfl(ev, j, 64);
        float ex = (j < rem) ? __expf(aj - m) : 0.f;
        acc = fmaf(ex, bufA[j], acc);
      }
      if (pf) {
#pragma unroll
        for (int j = 0; j < 8; ++j) bufA[j] = bufB[j];
        sv = svN; ev = evN;
      }
    }
  }
  out2[(size_t)node * 64 + lane] = acc * rd + b2[lane];  // H2=1: mean = identity
}

// ---------- pooling: sorted batch, wave handles 64 consecutive nodes ----------
__global__ __launch_bounds__(256) void k_pool(const float* __restrict__ out2,
                                              const int* __restrict__ batch,
                                              float* __restrict__ pooled,
                                              float* __restrict__ cnt, int n) {
  int wgl = blockIdx.x * 4 + (threadIdx.x >> 6);
  int lane = threadIdx.x & 63;
  int i0 = wgl * 64;
  if (i0 >= n) return;
  int i1 = min(i0 + 64, n);
  int cur = -1;
  float acc = 0.f, c = 0.f;
  for (int i = i0; i < i1; ++i) {
    int g = batch[i];
    if (g != cur) {
      if (cur >= 0) {
        atomicAdd(&pooled[cur * 64 + lane], acc);
        if (lane == 0) atomicAdd(&cnt[cur], c);
      }
      cur = g; acc = 0.f; c = 0.f;
    }
    acc += out2[(size_t)i * 64 + lane];
    c += 1.f;
  }
  if (cur >= 0) {
    atomicAdd(&pooled[cur * 64 + lane], acc);
    if (lane == 0) atomicAdd(&cnt[cur], c);
  }
}

// ---------- final: out[g,:] = (pooled[g,:]/cnt[g]) @ Pw + Pb ----------
__global__ __launch_bounds__(64) void k_final(const float* __restrict__ pooled,
                                              const float* __restrict__ cnt,
                                              const float* __restrict__ Pw,
                                              const float* __restrict__ Pb,
                                              float* __restrict__ out) {
  __shared__ float m[64];
  int g = blockIdx.x, o = threadIdx.x;
  m[o] = pooled[g * 64 + o] / fmaxf(cnt[g], 1.f);
  __syncthreads();
  float s = Pb[o];
#pragma unroll
  for (int c = 0; c < 64; ++c) s = fmaf(m[c], Pw[c * 64 + o], s);
  out[g * 64 + o] = s;
}

extern "C" void kernel_launch(void* const* d_in, const int* in_sizes, int n_in,
                              void* d_out, int out_size, void* d_ws, size_t ws_size,
                              hipStream_t stream) {
  const float* x         = (const float*)d_in[0];
  const int*   edge_index= (const int*)d_in[1];
  const float* edge_attr = (const float*)d_in[2];
  const int*   batch     = (const int*)d_in[3];
  const float* W1  = (const float*)d_in[4];
  const float* as1 = (const float*)d_in[5];
  const float* ad1 = (const float*)d_in[6];
  const float* We1 = (const float*)d_in[7];
  const float* ae1 = (const float*)d_in[8];
  const float* b1  = (const float*)d_in[9];
  const float* W2  = (const float*)d_in[10];
  const float* as2 = (const float*)d_in[11];
  const float* ad2 = (const float*)d_in[12];
  const float* We2 = (const float*)d_in[13];
  const float* ae2 = (const float*)d_in[14];
  const float* b2  = (const float*)d_in[15];
  const float* Pw  = (const float*)d_in[16];
  const float* Pb  = (const float*)d_in[17];

  const int N = in_sizes[0] / 128;
  const int E = in_sizes[1] / 2;
  const int G = out_size / 64;
  const int* srcI = edge_index;
  const int* dstI = edge_index + E;

  // ---- workspace layout (16B-aligned slots) ----
  float* ws = (float*)d_ws;
  size_t off = 0;
  auto alloc = [&](size_t elems) {
    float* p = ws + off;
    off += (elems + 3) & ~(size_t)3;
    return p;
  };
  int*   deg       = (int*)alloc(N);            // zeroed
  float* cnt       = alloc(G);                  // zeroed
  float* pooled    = alloc((size_t)G * 64);     // zeroed
  size_t zero_bytes = off * sizeof(float);
  int*   csr_off   = (int*)alloc(N + 1);
  int*   fill      = (int*)alloc(N);
  int*   bsum      = (int*)alloc(1024);
  int2*  pack      = (int2*)alloc((size_t)E * 2);   // {edge, src} per CSR slot
  float* eadot2    = alloc((size_t)E);
  float* loopdot2  = alloc((size_t)N);
  float* h         = alloc((size_t)N * 64);     // h1, reused as h2
  float* als       = alloc((size_t)N * 4);      // layer2 reuses first N
  float* ald       = alloc((size_t)N * 4);
  float* selfl     = alloc((size_t)N * 4);      // layer2 reuses first N
  float* elog      = alloc((size_t)E * 4);      // layer2 reuses first E
  float* outn      = alloc((size_t)N * 64);     // out1, reused as out2

  (void)ws_size; (void)n_in;
  hipMemsetAsync(d_ws, 0, zero_bytes, stream);

  const int ebl  = (E + 255) / 256;
  const int nb   = (N + 255) / 256;
  const int nbl4 = (N + 3) / 4;
  const int gemb = (N + 63) / 64;

  // CSR build (by dst)
  k_deg<<<ebl, 256, 0, stream>>>(dstI, deg, E);
  k_chunksum<<<nb, 256, 0, stream>>>(deg, bsum, N);
  k_bscan<<<1, 256, 0, stream>>>(bsum, nb, csr_off, N);
  k_chunkscan<<<nb, 256, 0, stream>>>(deg, bsum, csr_off, fill, N);
  k_scatter<<<ebl, 256, 0, stream>>>(dstI, srcI, fill, pack, E);

  // layer 1
  k_gemm<128, 4><<<gemb, 256, 0, stream>>>(x, W1, as1, ad1, h, als, ald, N);
  k_edgepass<<<nbl4, 256, 0, stream>>>(csr_off, pack, edge_attr, We1, ae1, We2, ae2,
                                       als, ald, elog, selfl, eadot2, loopdot2, N);
  k_agg1<<<nbl4, 256, 0, stream>>>(csr_off, pack, elog, selfl, h, b1, outn, N);

  // layer 2 (reuses h/als/ald/selfl/elog slots; out2 overwrites out1)
  k_gemm<64, 1><<<gemb, 256, 0, stream>>>(outn, W2, as2, ad2, h, als, ald, N);
  k_l2log<<<nbl4, 256, 0, stream>>>(csr_off, pack, eadot2, loopdot2, als, ald,
                                    elog, selfl, N);
  k_agg2<<<nbl4, 256, 0, stream>>>(csr_off, pack, elog, selfl, h, b2, outn, N);

  // pool + project
  k_pool<<<((N + 63) / 64 + 3) / 4, 256, 0, stream>>>(outn, batch, pooled, cnt, N);
  k_final<<<G, 64, 0, stream>>>(pooled, cnt, Pw, Pb, (float*)d_out);
}

// Round 6
// 321.900 us; speedup vs baseline: 1.1195x; 1.1195x over previous
//
#include <hip/hip_runtime.h>

#define LRELU(a) ((a) > 0.f ? (a) : 0.2f * (a))

// ---------- block-wide inclusive scan helper (256 threads, 4 waves) ----------
__device__ __forceinline__ int blockScanIncl256(int v, int* wl) {
  int t = threadIdx.x, lane = t & 63, w = t >> 6;
  int x = v;
#pragma unroll
  for (int o = 1; o < 64; o <<= 1) {
    int tmp = __shfl_up(x, (unsigned)o, 64);
    if (lane >= o) x += tmp;
  }
  if (lane == 63) wl[w] = x;
  __syncthreads();
  if (t == 0) {
    int s = 0;
#pragma unroll
    for (int j = 0; j < 4; ++j) { int tv = wl[j]; wl[j] = s; s += tv; }
  }
  __syncthreads();
  return x + wl[w];
}

// ---------- CSR build ----------
__global__ __launch_bounds__(256) void k_deg(const int* __restrict__ dst,
                                             int* __restrict__ deg, int E) {
  int e = blockIdx.x * 256 + threadIdx.x;
  if (e < E) atomicAdd(&deg[dst[e]], 1);
}

__global__ __launch_bounds__(256) void k_chunksum(const int* __restrict__ deg,
                                                  int* __restrict__ bsum, int n) {
  __shared__ int wl[4];
  int i = blockIdx.x * 256 + threadIdx.x;
  int v = (i < n) ? deg[i] : 0;
#pragma unroll
  for (int o = 1; o < 64; o <<= 1) v += __shfl_xor(v, o, 64);
  int lane = threadIdx.x & 63, w = threadIdx.x >> 6;
  if (lane == 0) wl[w] = v;
  __syncthreads();
  if (threadIdx.x == 0) bsum[blockIdx.x] = wl[0] + wl[1] + wl[2] + wl[3];
}

// single block; requires nb <= 256 (N <= 65536)
__global__ __launch_bounds__(256) void k_bscan(int* __restrict__ bsum, int nb,
                                               int* __restrict__ csr_off, int n) {
  __shared__ int wl[4];
  int t = threadIdx.x;
  int v = (t < nb) ? bsum[t] : 0;
  int incl = blockScanIncl256(v, wl);
  if (t < nb) bsum[t] = incl - v;  // exclusive block offsets
  if (t == 255) csr_off[n] = incl; // grand total
}

__global__ __launch_bounds__(256) void k_chunkscan(const int* __restrict__ deg,
                                                   const int* __restrict__ bsum,
                                                   int* __restrict__ csr_off,
                                                   int* __restrict__ fill, int n) {
  __shared__ int wl[4];
  int i = blockIdx.x * 256 + threadIdx.x;
  int v = (i < n) ? deg[i] : 0;
  int incl = blockScanIncl256(v, wl);
  int o = bsum[blockIdx.x] + incl - v;
  if (i < n) { csr_off[i] = o; fill[i] = o; }
}

// one scattered 8B write per edge: pack[p] = {edge_id, src}
__global__ __launch_bounds__(256) void k_scatter(const int* __restrict__ dst,
                                                 const int* __restrict__ src,
                                                 int* __restrict__ fill,
                                                 int2* __restrict__ pack, int E) {
  int e = blockIdx.x * 256 + threadIdx.x;
  if (e < E) {
    int d = dst[e];
    int p = atomicAdd(&fill[d], 1);
    pack[p] = make_int2(e, src[e]);
  }
}

// ---------- tiled f32 GEMM + fused attention-logit epilogue ----------
// H[b0:b0+64][0:64] = X[b0:b0+64][0:K] @ W[K][64]; als/ald = h . a per head.
// 256 threads = 16x16, each computes a 4x4 tile. X stride must equal K.
template <int K, int HH>
__global__ __launch_bounds__(256) void k_gemm(const float* __restrict__ X,
                                              const float* __restrict__ W,
                                              const float* __restrict__ a_s,
                                              const float* __restrict__ a_d,
                                              float* __restrict__ H,
                                              float* __restrict__ als,
                                              float* __restrict__ ald, int n) {
  __shared__ float Xs[64][K + 4];
  __shared__ float Ws[K][64];
  int t = threadIdx.x;
  int b0 = blockIdx.x * 64;
  for (int i = t; i < K * 64; i += 256) Ws[i >> 6][i & 63] = W[i];
  for (int i = t; i < 64 * K; i += 256) {
    int node = i / K, k = i % K;
    int r = b0 + node;
    Xs[node][k] = (r < n) ? X[(size_t)r * K + k] : 0.f;
  }
  __syncthreads();
  int tx = t & 15, ty = t >> 4;
  float acc[4][4] = {};
#pragma unroll 2
  for (int k4 = 0; k4 < K; k4 += 4) {
    float wvf[4][4];
#pragma unroll
    for (int j = 0; j < 4; ++j)
      *(float4*)&wvf[j][0] = *(const float4*)&Ws[k4 + j][tx * 4];
#pragma unroll
    for (int i = 0; i < 4; ++i) {
      float xvf[4];
      *(float4*)&xvf[0] = *(const float4*)&Xs[ty * 4 + i][k4];
#pragma unroll
      for (int kk = 0; kk < 4; ++kk)
#pragma unroll
        for (int j = 0; j < 4; ++j)
          acc[i][j] = fmaf(xvf[kk], wvf[kk][j], acc[i][j]);
    }
  }
#pragma unroll
  for (int i = 0; i < 4; ++i) {
    int node = b0 + ty * 4 + i;
    if (node < n)
      *(float4*)&H[(size_t)node * 64 + tx * 4] =
          make_float4(acc[i][0], acc[i][1], acc[i][2], acc[i][3]);
  }
  // ---- fused attention logits: als/ald[node*HH+head] ----
  constexpr int C = 64 / HH;     // channels per head
  constexpr int GL = C / 4;      // tx lanes per head group
  float asv[4], adv[4];
#pragma unroll
  for (int j = 0; j < 4; ++j) { asv[j] = a_s[tx * 4 + j]; adv[j] = a_d[tx * 4 + j]; }
#pragma unroll
  for (int i = 0; i < 4; ++i) {
    float ps = 0.f, pd = 0.f;
#pragma unroll
    for (int j = 0; j < 4; ++j) {
      ps = fmaf(acc[i][j], asv[j], ps);
      pd = fmaf(acc[i][j], adv[j], pd);
    }
#pragma unroll
    for (int o = 1; o < GL; o <<= 1) {
      ps += __shfl_xor(ps, o, 64);
      pd += __shfl_xor(pd, o, 64);
    }
    int node = b0 + ty * 4 + i;
    if (node < n && (tx & (GL - 1)) == 0) {
      int head = tx / GL;
      als[(size_t)node * HH + head] = ps;
      ald[(size_t)node * HH + head] = pd;
    }
  }
}

// ---------- fused CSR edge pass: each LANE owns one edge (no in-loop shfl) ----
// 16 lanes per node, 4 nodes per wave, 16 nodes per block. Produces:
//   elog1[i][h]   = LRELU(als1[s]+ald1[node]+ea@wa1[:,h])   (CSR order)
//   ed2csr[i]     = ea@wa2                                   (CSR order)
//   selfl1[node]  = LRELU(als1+ald1+mean(ea@wa1))            (linearity of dot)
//   loopdot2[node]= mean(ea@wa2)
__global__ __launch_bounds__(256) void k_csrlog(
    const int* __restrict__ csr_off, const int2* __restrict__ pack,
    const float* __restrict__ edge_attr,
    const float* __restrict__ We1, const float* __restrict__ ae1,
    const float* __restrict__ We2, const float* __restrict__ ae2,
    const float* __restrict__ als1, const float* __restrict__ ald1,
    float* __restrict__ elog1, float* __restrict__ selfl1,
    float* __restrict__ ed2csr, float* __restrict__ loopdot2, int n) {
  __shared__ float wa1s[64];  // [k*4+h] = sum_c We1[k,h*16+c]*ae1[h,c]
  __shared__ float wa2s[16];  // [k]     = sum_c We2[k,c]*ae2[c]
  int t = threadIdx.x;
  if (t < 64) {
    int k = t >> 2, hh = t & 3;
    float s = 0.f;
#pragma unroll
    for (int c = 0; c < 16; ++c) s = fmaf(We1[k * 64 + hh * 16 + c], ae1[hh * 16 + c], s);
    wa1s[t] = s;
  } else if (t < 80) {
    int k = t - 64;
    float s = 0.f;
#pragma unroll
    for (int c = 0; c < 64; ++c) s = fmaf(We2[k * 64 + c], ae2[c], s);
    wa2s[k] = s;
  }
  __syncthreads();
  int g = t >> 4, lane16 = t & 15;
  int node = blockIdx.x * 16 + g;
  if (node >= n) return;
  int s0 = csr_off[node], s1 = csr_off[node + 1];
  float4 adv = *(const float4*)(ald1 + (size_t)node * 4);  // uniform per group
  float4 sum1 = make_float4(0.f, 0.f, 0.f, 0.f);
  float sum2 = 0.f;
  for (int i = s0 + lane16; i < s1; i += 16) {
    int2 p = pack[i];
    const float4* ea = (const float4*)(edge_attr + (size_t)p.x * 16);
    float ev[16];
    *(float4*)&ev[0]  = ea[0];
    *(float4*)&ev[4]  = ea[1];
    *(float4*)&ev[8]  = ea[2];
    *(float4*)&ev[12] = ea[3];
    float d0 = 0.f, d1 = 0.f, d2 = 0.f, d3 = 0.f, q = 0.f;
#pragma unroll
    for (int k = 0; k < 16; ++k) {
      float4 w1 = *(const float4*)&wa1s[k * 4];
      d0 = fmaf(ev[k], w1.x, d0);
      d1 = fmaf(ev[k], w1.y, d1);
      d2 = fmaf(ev[k], w1.z, d2);
      d3 = fmaf(ev[k], w1.w, d3);
      q  = fmaf(ev[k], wa2s[k], q);
    }
    sum1.x += d0; sum1.y += d1; sum1.z += d2; sum1.w += d3; sum2 += q;
    float4 asv = *(const float4*)(als1 + (size_t)p.y * 4);
    float l0 = asv.x + adv.x + d0;
    float l1 = asv.y + adv.y + d1;
    float l2 = asv.z + adv.z + d2;
    float l3 = asv.w + adv.w + d3;
    *(float4*)&elog1[(size_t)i * 4] =
        make_float4(LRELU(l0), LRELU(l1), LRELU(l2), LRELU(l3));
    ed2csr[i] = q;
  }
  // once-per-node reduction over the 16-lane group (xor<16 stays in group)
#pragma unroll
  for (int o = 1; o < 16; o <<= 1) {
    sum1.x += __shfl_xor(sum1.x, o, 64);
    sum1.y += __shfl_xor(sum1.y, o, 64);
    sum1.z += __shfl_xor(sum1.z, o, 64);
    sum1.w += __shfl_xor(sum1.w, o, 64);
    sum2   += __shfl_xor(sum2,   o, 64);
  }
  if (lane16 == 0) {
    float cd = fmaxf((float)(s1 - s0), 1.f);
    float4 asn = *(const float4*)(als1 + (size_t)node * 4);
    float l0 = asn.x + adv.x + sum1.x / cd;
    float l1 = asn.y + adv.y + sum1.y / cd;
    float l2 = asn.z + adv.z + sum1.z / cd;
    float l3 = asn.w + adv.w + sum1.w / cd;
    *(float4*)&selfl1[(size_t)node * 4] =
        make_float4(LRELU(l0), LRELU(l1), LRELU(l2), LRELU(l3));
    loopdot2[node] = sum2 / cd;
  }
}

// ---------- layer 1 aggregation ----------
// phase 1: exact segment max+denom from sequential elog reads (lanes = 16 edges x 4 heads)
// phase 2: batched (8-deep, double-buffered) h gathers, pure exp*fma accumulation
__global__ __launch_bounds__(256) void k_agg1(const int* __restrict__ csr_off,
                                              const int2* __restrict__ pack,
                                              const float* __restrict__ elog,
                                              const float* __restrict__ selfl,
                                              const float* __restrict__ h1,
                                              const float* __restrict__ b1,
                                              float* __restrict__ out1, int n) {
  int t = threadIdx.x, w = t >> 6, lane = t & 63;
  int node = blockIdx.x * 4 + w;
  if (node >= n) return;
  int s0 = csr_off[node], s1 = csr_off[node + 1];
  int nit = s1 - s0;
  // ---- phase 1 ----
  int h4 = lane & 3;
  float sl4 = selfl[node * 4 + h4];
  float m = sl4;
  for (int i = s0 + (lane >> 2); i < s1; i += 16)
    m = fmaxf(m, elog[(size_t)i * 4 + h4]);
#pragma unroll
  for (int o = 4; o < 64; o <<= 1) m = fmaxf(m, __shfl_xor(m, o, 64));
  float den = ((lane >> 2) == 0) ? __expf(sl4 - m) : 0.f;
  for (int i = s0 + (lane >> 2); i < s1; i += 16)
    den += __expf(elog[(size_t)i * 4 + h4] - m);
#pragma unroll
  for (int o = 4; o < 64; o <<= 1) den += __shfl_xor(den, o, 64);
  int head = lane >> 4;  // head in channel layout
  float m_ch = __shfl(m, head, 64);
  float rd_ch = 1.f / __shfl(den, head, 64);
  float sl_ch = __shfl(sl4, head, 64);
  float acc = __expf(sl_ch - m_ch) * h1[(size_t)node * 64 + lane];
  // ---- phase 2 ----
  if (nit > 0) {
    int nb = (nit + 7) >> 3;
    int laneE = lane & 7, laneB = (lane >> 2) & 7, laneH = lane & 3;
    int sv; float ev;
    float bufA[8], bufB[8];
    {
      int i1 = min(s0 + laneE, s1 - 1);
      sv = pack[i1].y;
      int i2 = min(s0 + laneB, s1 - 1);
      ev = elog[(size_t)i2 * 4 + laneH];
    }
#pragma unroll
    for (int j = 0; j < 8; ++j)
      bufA[j] = h1[(size_t)__shfl(sv, j, 64) * 64 + lane];
    for (int b = 0; b < nb; ++b) {
      int svN = 0; float evN = 0.f;
      bool pf = (b + 1 < nb);
      if (pf) {
        int base = s0 + (b + 1) * 8;
        int i1 = min(base + laneE, s1 - 1);
        svN = pack[i1].y;
        int i2 = min(base + laneB, s1 - 1);
        evN = elog[(size_t)i2 * 4 + laneH];
#pragma unroll
        for (int j = 0; j < 8; ++j)
          bufB[j] = h1[(size_t)__shfl(svN, j, 64) * 64 + lane];
      }
      int rem = nit - b * 8;
#pragma unroll
      for (int j = 0; j < 8; ++j) {
        float aj = __shfl(ev, j * 4 + head, 64);
        float ex = (j < rem) ? __expf(aj - m_ch) : 0.f;
        acc = fmaf(ex, bufA[j], acc);
      }
      if (pf) {
#pragma unroll
        for (int j = 0; j < 8; ++j) bufA[j] = bufB[j];
        sv = svN; ev = evN;
      }
    }
  }
  float r = acc * rd_ch + b1[lane];
  out1[(size_t)node * 64 + lane] = r > 0.f ? r : expm1f(r);  // ELU fused
}

// ---------- layer 2 logits: wave per node (dst = node), no edge_attr read ----------
__global__ __launch_bounds__(256) void k_l2log(const int* __restrict__ csr_off,
                                               const int2* __restrict__ pack,
                                               const float* __restrict__ eadot2,
                                               const float* __restrict__ loopdot2,
                                               const float* __restrict__ als2,
                                               const float* __restrict__ ald2,
                                               float* __restrict__ elog2,
                                               float* __restrict__ selfl2, int n) {
  int t = threadIdx.x, w = t >> 6, lane = t & 63;
  int node = blockIdx.x * 4 + w;
  if (node >= n) return;
  float adv = ald2[node];
  if (lane == 0) {
    float lg = als2[node] + adv + loopdot2[node];
    selfl2[node] = LRELU(lg);
  }
  int s0 = csr_off[node], s1 = csr_off[node + 1];
  for (int i = s0 + lane; i < s1; i += 64) {
    int s = pack[i].y;
    float lg = als2[s] + adv + eadot2[i];
    elog2[i] = LRELU(lg);
  }
}

// ---------- layer 2 aggregation (scalar head) ----------
__global__ __launch_bounds__(256) void k_agg2(const int* __restrict__ csr_off,
                                              const int2* __restrict__ pack,
                                              const float* __restrict__ elog,
                                              const float* __restrict__ selfl,
                                              const float* __restrict__ h2,
                                              const float* __restrict__ b2,
                                              float* __restrict__ out2, int n) {
  int t = threadIdx.x, w = t >> 6, lane = t & 63;
  int node = blockIdx.x * 4 + w;
  if (node >= n) return;
  int s0 = csr_off[node], s1 = csr_off[node + 1];
  int nit = s1 - s0;
  // ---- phase 1 ----
  float sl = selfl[node];
  float m = sl;
  for (int i = s0 + lane; i < s1; i += 64) m = fmaxf(m, elog[i]);
#pragma unroll
  for (int o = 1; o < 64; o <<= 1) m = fmaxf(m, __shfl_xor(m, o, 64));
  float den = (lane == 0) ? __expf(sl - m) : 0.f;
  for (int i = s0 + lane; i < s1; i += 64) den += __expf(elog[i] - m);
#pragma unroll
  for (int o = 1; o < 64; o <<= 1) den += __shfl_xor(den, o, 64);
  float rd = 1.f / den;
  float acc = __expf(sl - m) * h2[(size_t)node * 64 + lane];
  // ---- phase 2 ----
  if (nit > 0) {
    int nb = (nit + 7) >> 3;
    int laneE = lane & 7;
    int sv; float ev;
    {
      int i1 = min(s0 + laneE, s1 - 1);
      sv = pack[i1].y;
      ev = elog[i1];
    }
    float bufA[8], bufB[8];
#pragma unroll
    for (int j = 0; j < 8; ++j)
      bufA[j] = h2[(size_t)__shfl(sv, j, 64) * 64 + lane];
    for (int b = 0; b < nb; ++b) {
      int svN = 0; float evN = 0.f;
      bool pf = (b + 1 < nb);
      if (pf) {
        int i1 = min(s0 + (b + 1) * 8 + laneE, s1 - 1);
        svN = pack[i1].y;
        evN = elog[i1];
#pragma unroll
        for (int j = 0; j < 8; ++j)
          bufB[j] = h2[(size_t)__shfl(svN, j, 64) * 64 + lane];
      }
      int rem = nit - b * 8;
#pragma unroll
      for (int j = 0; j < 8; ++j) {
        float aj = __shfl(ev, j, 64);
        float ex = (j < rem) ? __expf(aj - m) : 0.f;
        acc = fmaf(ex, bufA[j], acc);
      }
      if (pf) {
#pragma unroll
        for (int j = 0; j < 8; ++j) bufA[j] = bufB[j];
        sv = svN; ev = evN;
      }
    }
  }
  out2[(size_t)node * 64 + lane] = acc * rd + b2[lane];  // H2=1: mean = identity
}

// ---------- pooling: sorted batch, wave handles 64 consecutive nodes ----------
__global__ __launch_bounds__(256) void k_pool(const float* __restrict__ out2,
                                              const int* __restrict__ batch,
                                              float* __restrict__ pooled,
                                              float* __restrict__ cnt, int n) {
  int wgl = blockIdx.x * 4 + (threadIdx.x >> 6);
  int lane = threadIdx.x & 63;
  int i0 = wgl * 64;
  if (i0 >= n) return;
  int i1 = min(i0 + 64, n);
  int cur = -1;
  float acc = 0.f, c = 0.f;
  for (int i = i0; i < i1; ++i) {
    int g = batch[i];
    if (g != cur) {
      if (cur >= 0) {
        atomicAdd(&pooled[cur * 64 + lane], acc);
        if (lane == 0) atomicAdd(&cnt[cur], c);
      }
      cur = g; acc = 0.f; c = 0.f;
    }
    acc += out2[(size_t)i * 64 + lane];
    c += 1.f;
  }
  if (cur >= 0) {
    atomicAdd(&pooled[cur * 64 + lane], acc);
    if (lane == 0) atomicAdd(&cnt[cur], c);
  }
}

// ---------- final: out[g,:] = (pooled[g,:]/cnt[g]) @ Pw + Pb ----------
__global__ __launch_bounds__(64) void k_final(const float* __restrict__ pooled,
                                              const float* __restrict__ cnt,
                                              const float* __restrict__ Pw,
                                              const float* __restrict__ Pb,
                                              float* __restrict__ out) {
  __shared__ float m[64];
  int g = blockIdx.x, o = threadIdx.x;
  m[o] = pooled[g * 64 + o] / fmaxf(cnt[g], 1.f);
  __syncthreads();
  float s = Pb[o];
#pragma unroll
  for (int c = 0; c < 64; ++c) s = fmaf(m[c], Pw[c * 64 + o], s);
  out[g * 64 + o] = s;
}

extern "C" void kernel_launch(void* const* d_in, const int* in_sizes, int n_in,
                              void* d_out, int out_size, void* d_ws, size_t ws_size,
                              hipStream_t stream) {
  const float* x         = (const float*)d_in[0];
  const int*   edge_index= (const int*)d_in[1];
  const float* edge_attr = (const float*)d_in[2];
  const int*   batch     = (const int*)d_in[3];
  const float* W1  = (const float*)d_in[4];
  const float* as1 = (const float*)d_in[5];
  const float* ad1 = (const float*)d_in[6];
  const float* We1 = (const float*)d_in[7];
  const float* ae1 = (const float*)d_in[8];
  const float* b1  = (const float*)d_in[9];
  const float* W2  = (const float*)d_in[10];
  const float* as2 = (const float*)d_in[11];
  const float* ad2 = (const float*)d_in[12];
  const float* We2 = (const float*)d_in[13];
  const float* ae2 = (const float*)d_in[14];
  const float* b2  = (const float*)d_in[15];
  const float* Pw  = (const float*)d_in[16];
  const float* Pb  = (const float*)d_in[17];

  const int N = in_sizes[0] / 128;
  const int E = in_sizes[1] / 2;
  const int G = out_size / 64;
  const int* srcI = edge_index;
  const int* dstI = edge_index + E;

  // ---- workspace layout (16B-aligned slots) ----
  float* ws = (float*)d_ws;
  size_t off = 0;
  auto alloc = [&](size_t elems) {
    float* p = ws + off;
    off += (elems + 3) & ~(size_t)3;
    return p;
  };
  int*   deg       = (int*)alloc(N);            // zeroed
  float* cnt       = alloc(G);                  // zeroed
  float* pooled    = alloc((size_t)G * 64);     // zeroed
  size_t zero_bytes = off * sizeof(float);
  int*   csr_off   = (int*)alloc(N + 1);
  int*   fill      = (int*)alloc(N);
  int*   bsum      = (int*)alloc(1024);
  int2*  pack      = (int2*)alloc((size_t)E * 2);   // {edge, src} per CSR slot
  float* ed2csr    = alloc((size_t)E);
  float* loopdot2  = alloc((size_t)N);
  float* h         = alloc((size_t)N * 64);     // h1, reused as h2
  float* als       = alloc((size_t)N * 4);      // layer2 reuses first N
  float* ald       = alloc((size_t)N * 4);
  float* selfl     = alloc((size_t)N * 4);      // layer2 reuses first N
  float* elog      = alloc((size_t)E * 4);      // layer2 reuses first E
  float* outn      = alloc((size_t)N * 64);     // out1, reused as out2

  (void)ws_size; (void)n_in;
  hipMemsetAsync(d_ws, 0, zero_bytes, stream);

  const int ebl   = (E + 255) / 256;
  const int nb    = (N + 255) / 256;
  const int nbl4  = (N + 3) / 4;
  const int nbl16 = (N + 15) / 16;
  const int gemb  = (N + 63) / 64;

  // CSR build (by dst)
  k_deg<<<ebl, 256, 0, stream>>>(dstI, deg, E);
  k_chunksum<<<nb, 256, 0, stream>>>(deg, bsum, N);
  k_bscan<<<1, 256, 0, stream>>>(bsum, nb, csr_off, N);
  k_chunkscan<<<nb, 256, 0, stream>>>(deg, bsum, csr_off, fill, N);
  k_scatter<<<ebl, 256, 0, stream>>>(dstI, srcI, fill, pack, E);

  // layer 1
  k_gemm<128, 4><<<gemb, 256, 0, stream>>>(x, W1, as1, ad1, h, als, ald, N);
  k_csrlog<<<nbl16, 256, 0, stream>>>(csr_off, pack, edge_attr, We1, ae1, We2, ae2,
                                      als, ald, elog, selfl, ed2csr, loopdot2, N);
  k_agg1<<<nbl4, 256, 0, stream>>>(csr_off, pack, elog, selfl, h, b1, outn, N);

  // layer 2 (reuses h/als/ald/selfl/elog slots; out2 overwrites out1)
  k_gemm<64, 1><<<gemb, 256, 0, stream>>>(outn, W2, as2, ad2, h, als, ald, N);
  k_l2log<<<nbl4, 256, 0, stream>>>(csr_off, pack, ed2csr, loopdot2, als, ald,
                                    elog, selfl, N);
  k_agg2<<<nbl4, 256, 0, stream>>>(csr_off, pack, elog, selfl, h, b2, outn, N);

  // pool + project
  k_pool<<<((N + 63) / 64 + 3) / 4, 256, 0, stream>>>(outn, batch, pooled, cnt, N);
  k_final<<<G, 64, 0, stream>>>(pooled, cnt, Pw, Pb, (float*)d_out);
}

// Round 7
// 287.381 us; speedup vs baseline: 1.2539x; 1.1201x over previous
//
#include <hip/hip_runtime.h>

#define LRELU(a) ((a) > 0.f ? (a) : 0.2f * (a))

// ---------- block-wide inclusive scan helper (256 threads, 4 waves) ----------
__device__ __forceinline__ int blockScanIncl256(int v, int* wl) {
  int t = threadIdx.x, lane = t & 63, w = t >> 6;
  int x = v;
#pragma unroll
  for (int o = 1; o < 64; o <<= 1) {
    int tmp = __shfl_up(x, (unsigned)o, 64);
    if (lane >= o) x += tmp;
  }
  if (lane == 63) wl[w] = x;
  __syncthreads();
  if (t == 0) {
    int s = 0;
#pragma unroll
    for (int j = 0; j < 4; ++j) { int tv = wl[j]; wl[j] = s; s += tv; }
  }
  __syncthreads();
  return x + wl[w];
}

// ---------- CSR build ----------
__global__ __launch_bounds__(256) void k_deg(const int* __restrict__ dst,
                                             int* __restrict__ deg, int E) {
  int e = blockIdx.x * 256 + threadIdx.x;
  if (e < E) atomicAdd(&deg[dst[e]], 1);
}

__global__ __launch_bounds__(256) void k_chunksum(const int* __restrict__ deg,
                                                  int* __restrict__ bsum, int n) {
  __shared__ int wl[4];
  int i = blockIdx.x * 256 + threadIdx.x;
  int v = (i < n) ? deg[i] : 0;
#pragma unroll
  for (int o = 1; o < 64; o <<= 1) v += __shfl_xor(v, o, 64);
  int lane = threadIdx.x & 63, w = threadIdx.x >> 6;
  if (lane == 0) wl[w] = v;
  __syncthreads();
  if (threadIdx.x == 0) bsum[blockIdx.x] = wl[0] + wl[1] + wl[2] + wl[3];
}

// single block; requires nb <= 256 (N <= 65536)
__global__ __launch_bounds__(256) void k_bscan(int* __restrict__ bsum, int nb,
                                               int* __restrict__ csr_off, int n) {
  __shared__ int wl[4];
  int t = threadIdx.x;
  int v = (t < nb) ? bsum[t] : 0;
  int incl = blockScanIncl256(v, wl);
  if (t < nb) bsum[t] = incl - v;  // exclusive block offsets
  if (t == 255) csr_off[n] = incl; // grand total
}

__global__ __launch_bounds__(256) void k_chunkscan(const int* __restrict__ deg,
                                                   const int* __restrict__ bsum,
                                                   int* __restrict__ csr_off,
                                                   int* __restrict__ fill, int n) {
  __shared__ int wl[4];
  int i = blockIdx.x * 256 + threadIdx.x;
  int v = (i < n) ? deg[i] : 0;
  int incl = blockScanIncl256(v, wl);
  int o = bsum[blockIdx.x] + incl - v;
  if (i < n) { csr_off[i] = o; fill[i] = o; }
}

// ---------- chunked-K tiled f32 GEMM body + fused attention-logit epilogue ----
// H[b0:b0+64][0:64] = X[b0:b0+64][0:K] @ W[K][64]; als/ald = h . a per head.
// 256 threads = 16x16, each computes a 4x4 tile. LDS ~17.5KB -> 8 blocks/CU.
template <int K, int HH>
__device__ __forceinline__ void gemm_body(const float* __restrict__ X,
                                          const float* __restrict__ W,
                                          const float* __restrict__ a_s,
                                          const float* __restrict__ a_d,
                                          float* __restrict__ H,
                                          float* __restrict__ als,
                                          float* __restrict__ ald,
                                          int n, int bid) {
  constexpr int KC = 32;
  __shared__ float Xs[64][KC + 4];   // 9216 B
  __shared__ float Ws[KC][64 + 4];   // 8704 B (padded rows: avoid write conflicts)
  int t = threadIdx.x;
  int b0 = bid * 64;
  int tx = t & 15, ty = t >> 4;
  float acc[4][4] = {};
  for (int kc = 0; kc < K; kc += KC) {
    if (kc) __syncthreads();
    // stage X chunk: 64 rows x 32 k, 8 floats/thread (2x float4)
    {
      int i = t * 8;
      int node = i >> 5, k = i & 31;
      int r = b0 + node;
      float4 v0 = make_float4(0.f, 0.f, 0.f, 0.f), v1 = v0;
      if (r < n) {
        const float* src = X + (size_t)r * K + kc + k;
        v0 = *(const float4*)src;
        v1 = *(const float4*)(src + 4);
      }
      *(float4*)&Xs[node][k] = v0;
      *(float4*)&Xs[node][k + 4] = v1;
    }
    // stage W chunk: 32 rows x 64 c, 8 floats/thread
    {
      int i = t * 8;
      int kk = i >> 6, c = i & 63;
      const float* src = W + (size_t)(kc + kk) * 64 + c;
      *(float4*)&Ws[kk][c] = *(const float4*)src;
      *(float4*)&Ws[kk][c + 4] = *(const float4*)(src + 4);
    }
    __syncthreads();
#pragma unroll
    for (int k4 = 0; k4 < KC; k4 += 4) {
      float wvf[4][4];
#pragma unroll
      for (int j = 0; j < 4; ++j)
        *(float4*)&wvf[j][0] = *(const float4*)&Ws[k4 + j][tx * 4];
#pragma unroll
      for (int i = 0; i < 4; ++i) {
        float xvf[4];
        *(float4*)&xvf[0] = *(const float4*)&Xs[ty * 4 + i][k4];
#pragma unroll
        for (int kk = 0; kk < 4; ++kk)
#pragma unroll
          for (int j = 0; j < 4; ++j)
            acc[i][j] = fmaf(xvf[kk], wvf[kk][j], acc[i][j]);
      }
    }
  }
#pragma unroll
  for (int i = 0; i < 4; ++i) {
    int node = b0 + ty * 4 + i;
    if (node < n)
      *(float4*)&H[(size_t)node * 64 + tx * 4] =
          make_float4(acc[i][0], acc[i][1], acc[i][2], acc[i][3]);
  }
  // ---- fused attention logits: als/ald[node*HH+head] ----
  constexpr int C = 64 / HH;     // channels per head
  constexpr int GL = C / 4;      // tx lanes per head group
  float asv[4], adv[4];
#pragma unroll
  for (int j = 0; j < 4; ++j) { asv[j] = a_s[tx * 4 + j]; adv[j] = a_d[tx * 4 + j]; }
#pragma unroll
  for (int i = 0; i < 4; ++i) {
    float ps = 0.f, pd = 0.f;
#pragma unroll
    for (int j = 0; j < 4; ++j) {
      ps = fmaf(acc[i][j], asv[j], ps);
      pd = fmaf(acc[i][j], adv[j], pd);
    }
#pragma unroll
    for (int o = 1; o < GL; o <<= 1) {
      ps += __shfl_xor(ps, o, 64);
      pd += __shfl_xor(pd, o, 64);
    }
    int node = b0 + ty * 4 + i;
    if (node < n && (tx & (GL - 1)) == 0) {
      int head = tx / GL;
      als[(size_t)node * HH + head] = ps;
      ald[(size_t)node * HH + head] = pd;
    }
  }
}

__global__ __launch_bounds__(256) void k_gemm2(const float* __restrict__ X,
                                               const float* __restrict__ W,
                                               const float* __restrict__ a_s,
                                               const float* __restrict__ a_d,
                                               float* __restrict__ H,
                                               float* __restrict__ als,
                                               float* __restrict__ ald, int n) {
  gemm_body<64, 1>(X, W, a_s, a_d, H, als, ald, n, blockIdx.x);
}

// ---------- fused: gemm1 (blocks < gemmBlocks) || CSR scatter (the rest) ----------
// scatter: one 8B write per edge pack[p]={edge,src}, 2 edges/thread for MLP.
__global__ __launch_bounds__(256) void k_gs(const float* __restrict__ X,
                                            const float* __restrict__ W,
                                            const float* __restrict__ a_s,
                                            const float* __restrict__ a_d,
                                            float* __restrict__ H,
                                            float* __restrict__ als,
                                            float* __restrict__ ald, int n,
                                            int gemmBlocks,
                                            const int* __restrict__ dst,
                                            const int* __restrict__ src,
                                            int* __restrict__ fill,
                                            int2* __restrict__ pack, int E) {
  if ((int)blockIdx.x < gemmBlocks) {
    gemm_body<128, 4>(X, W, a_s, a_d, H, als, ald, n, blockIdx.x);
  } else {
    int base = (blockIdx.x - gemmBlocks) * 512 + threadIdx.x;
    int e0 = base, e1 = base + 256;
    int d0 = 0, d1 = 0;
    if (e0 < E) d0 = dst[e0];
    if (e1 < E) d1 = dst[e1];
    if (e0 < E) {
      int p = atomicAdd(&fill[d0], 1);
      pack[p] = make_int2(e0, src[e0]);
    }
    if (e1 < E) {
      int p = atomicAdd(&fill[d1], 1);
      pack[p] = make_int2(e1, src[e1]);
    }
  }
}

// ---------- fused CSR edge pass: each LANE owns one edge (no in-loop shfl) ----
// 16 lanes per node, 16 nodes per block. Produces:
//   elog1[i][h]   = LRELU(als1[s]+ald1[node]+ea@wa1[:,h])   (CSR order)
//   ed2csr[i]     = ea@wa2                                   (CSR order)
//   selfl1[node]  = LRELU(als1+ald1+mean(ea@wa1))            (linearity of dot)
//   loopdot2[node]= mean(ea@wa2)
__global__ __launch_bounds__(256) void k_csrlog(
    const int* __restrict__ csr_off, const int2* __restrict__ pack,
    const float* __restrict__ edge_attr,
    const float* __restrict__ We1, const float* __restrict__ ae1,
    const float* __restrict__ We2, const float* __restrict__ ae2,
    const float* __restrict__ als1, const float* __restrict__ ald1,
    float* __restrict__ elog1, float* __restrict__ selfl1,
    float* __restrict__ ed2csr, float* __restrict__ loopdot2, int n) {
  __shared__ float wa1s[64];  // [k*4+h] = sum_c We1[k,h*16+c]*ae1[h,c]
  __shared__ float wa2s[16];  // [k]     = sum_c We2[k,c]*ae2[c]
  int t = threadIdx.x;
  if (t < 64) {
    int k = t >> 2, hh = t & 3;
    float s = 0.f;
#pragma unroll
    for (int c = 0; c < 16; ++c) s = fmaf(We1[k * 64 + hh * 16 + c], ae1[hh * 16 + c], s);
    wa1s[t] = s;
  } else if (t < 80) {
    int k = t - 64;
    float s = 0.f;
#pragma unroll
    for (int c = 0; c < 64; ++c) s = fmaf(We2[k * 64 + c], ae2[c], s);
    wa2s[k] = s;
  }
  __syncthreads();
  int g = t >> 4, lane16 = t & 15;
  int node = blockIdx.x * 16 + g;
  if (node >= n) return;
  int s0 = csr_off[node], s1 = csr_off[node + 1];
  float4 adv = *(const float4*)(ald1 + (size_t)node * 4);  // uniform per group
  float4 sum1 = make_float4(0.f, 0.f, 0.f, 0.f);
  float sum2 = 0.f;
  for (int i = s0 + lane16; i < s1; i += 16) {
    int2 p = pack[i];
    const float4* ea = (const float4*)(edge_attr + (size_t)p.x * 16);
    float ev[16];
    *(float4*)&ev[0]  = ea[0];
    *(float4*)&ev[4]  = ea[1];
    *(float4*)&ev[8]  = ea[2];
    *(float4*)&ev[12] = ea[3];
    float d0 = 0.f, d1 = 0.f, d2 = 0.f, d3 = 0.f, q = 0.f;
#pragma unroll
    for (int k = 0; k < 16; ++k) {
      float4 w1 = *(const float4*)&wa1s[k * 4];
      d0 = fmaf(ev[k], w1.x, d0);
      d1 = fmaf(ev[k], w1.y, d1);
      d2 = fmaf(ev[k], w1.z, d2);
      d3 = fmaf(ev[k], w1.w, d3);
      q  = fmaf(ev[k], wa2s[k], q);
    }
    sum1.x += d0; sum1.y += d1; sum1.z += d2; sum1.w += d3; sum2 += q;
    float4 asv = *(const float4*)(als1 + (size_t)p.y * 4);
    float l0 = asv.x + adv.x + d0;
    float l1 = asv.y + adv.y + d1;
    float l2 = asv.z + adv.z + d2;
    float l3 = asv.w + adv.w + d3;
    *(float4*)&elog1[(size_t)i * 4] =
        make_float4(LRELU(l0), LRELU(l1), LRELU(l2), LRELU(l3));
    ed2csr[i] = q;
  }
  // once-per-node reduction over the 16-lane group (xor<16 stays in group)
#pragma unroll
  for (int o = 1; o < 16; o <<= 1) {
    sum1.x += __shfl_xor(sum1.x, o, 64);
    sum1.y += __shfl_xor(sum1.y, o, 64);
    sum1.z += __shfl_xor(sum1.z, o, 64);
    sum1.w += __shfl_xor(sum1.w, o, 64);
    sum2   += __shfl_xor(sum2,   o, 64);
  }
  if (lane16 == 0) {
    float cd = fmaxf((float)(s1 - s0), 1.f);
    float4 asn = *(const float4*)(als1 + (size_t)node * 4);
    float l0 = asn.x + adv.x + sum1.x / cd;
    float l1 = asn.y + adv.y + sum1.y / cd;
    float l2 = asn.z + adv.z + sum1.z / cd;
    float l3 = asn.w + adv.w + sum1.w / cd;
    *(float4*)&selfl1[(size_t)node * 4] =
        make_float4(LRELU(l0), LRELU(l1), LRELU(l2), LRELU(l3));
    loopdot2[node] = sum2 / cd;
  }
}

// ---------- layer 1 aggregation ----------
// phase 1: exact segment max+denom from sequential elog reads (lanes = 16 edges x 4 heads)
// phase 2: batched (8-deep, double-buffered) h gathers, pure exp*fma accumulation
__global__ __launch_bounds__(256) void k_agg1(const int* __restrict__ csr_off,
                                              const int2* __restrict__ pack,
                                              const float* __restrict__ elog,
                                              const float* __restrict__ selfl,
                                              const float* __restrict__ h1,
                                              const float* __restrict__ b1,
                                              float* __restrict__ out1, int n) {
  int t = threadIdx.x, w = t >> 6, lane = t & 63;
  int node = blockIdx.x * 4 + w;
  if (node >= n) return;
  int s0 = csr_off[node], s1 = csr_off[node + 1];
  int nit = s1 - s0;
  // ---- phase 1 ----
  int h4 = lane & 3;
  float sl4 = selfl[node * 4 + h4];
  float m = sl4;
  for (int i = s0 + (lane >> 2); i < s1; i += 16)
    m = fmaxf(m, elog[(size_t)i * 4 + h4]);
#pragma unroll
  for (int o = 4; o < 64; o <<= 1) m = fmaxf(m, __shfl_xor(m, o, 64));
  float den = ((lane >> 2) == 0) ? __expf(sl4 - m) : 0.f;
  for (int i = s0 + (lane >> 2); i < s1; i += 16)
    den += __expf(elog[(size_t)i * 4 + h4] - m);
#pragma unroll
  for (int o = 4; o < 64; o <<= 1) den += __shfl_xor(den, o, 64);
  int head = lane >> 4;  // head in channel layout
  float m_ch = __shfl(m, head, 64);
  float rd_ch = 1.f / __shfl(den, head, 64);
  float sl_ch = __shfl(sl4, head, 64);
  float acc = __expf(sl_ch - m_ch) * h1[(size_t)node * 64 + lane];
  // ---- phase 2 ----
  if (nit > 0) {
    int nb = (nit + 7) >> 3;
    int laneE = lane & 7, laneB = (lane >> 2) & 7, laneH = lane & 3;
    int sv; float ev;
    float bufA[8], bufB[8];
    {
      int i1 = min(s0 + laneE, s1 - 1);
      sv = pack[i1].y;
      int i2 = min(s0 + laneB, s1 - 1);
      ev = elog[(size_t)i2 * 4 + laneH];
    }
#pragma unroll
    for (int j = 0; j < 8; ++j)
      bufA[j] = h1[(size_t)__shfl(sv, j, 64) * 64 + lane];
    for (int b = 0; b < nb; ++b) {
      int svN = 0; float evN = 0.f;
      bool pf = (b + 1 < nb);
      if (pf) {
        int base = s0 + (b + 1) * 8;
        int i1 = min(base + laneE, s1 - 1);
        svN = pack[i1].y;
        int i2 = min(base + laneB, s1 - 1);
        evN = elog[(size_t)i2 * 4 + laneH];
#pragma unroll
        for (int j = 0; j < 8; ++j)
          bufB[j] = h1[(size_t)__shfl(svN, j, 64) * 64 + lane];
      }
      int rem = nit - b * 8;
#pragma unroll
      for (int j = 0; j < 8; ++j) {
        float aj = __shfl(ev, j * 4 + head, 64);
        float ex = (j < rem) ? __expf(aj - m_ch) : 0.f;
        acc = fmaf(ex, bufA[j], acc);
      }
      if (pf) {
#pragma unroll
        for (int j = 0; j < 8; ++j) bufA[j] = bufB[j];
        sv = svN; ev = evN;
      }
    }
  }
  float r = acc * rd_ch + b1[lane];
  out1[(size_t)node * 64 + lane] = r > 0.f ? r : expm1f(r);  // ELU fused
}

// ---------- layer 2 logits: wave per node (dst = node), no edge_attr read ----------
__global__ __launch_bounds__(256) void k_l2log(const int* __restrict__ csr_off,
                                               const int2* __restrict__ pack,
                                               const float* __restrict__ eadot2,
                                               const float* __restrict__ loopdot2,
                                               const float* __restrict__ als2,
                                               const float* __restrict__ ald2,
                                               float* __restrict__ elog2,
                                               float* __restrict__ selfl2, int n) {
  int t = threadIdx.x, w = t >> 6, lane = t & 63;
  int node = blockIdx.x * 4 + w;
  if (node >= n) return;
  float adv = ald2[node];
  if (lane == 0) {
    float lg = als2[node] + adv + loopdot2[node];
    selfl2[node] = LRELU(lg);
  }
  int s0 = csr_off[node], s1 = csr_off[node + 1];
  for (int i = s0 + lane; i < s1; i += 64) {
    int s = pack[i].y;
    float lg = als2[s] + adv + eadot2[i];
    elog2[i] = LRELU(lg);
  }
}

// ---------- layer 2 aggregation (scalar head) ----------
__global__ __launch_bounds__(256) void k_agg2(const int* __restrict__ csr_off,
                                              const int2* __restrict__ pack,
                                              const float* __restrict__ elog,
                                              const float* __restrict__ selfl,
                                              const float* __restrict__ h2,
                                              const float* __restrict__ b2,
                                              float* __restrict__ out2, int n) {
  int t = threadIdx.x, w = t >> 6, lane = t & 63;
  int node = blockIdx.x * 4 + w;
  if (node >= n) return;
  int s0 = csr_off[node], s1 = csr_off[node + 1];
  int nit = s1 - s0;
  // ---- phase 1 ----
  float sl = selfl[node];
  float m = sl;
  for (int i = s0 + lane; i < s1; i += 64) m = fmaxf(m, elog[i]);
#pragma unroll
  for (int o = 1; o < 64; o <<= 1) m = fmaxf(m, __shfl_xor(m, o, 64));
  float den = (lane == 0) ? __expf(sl - m) : 0.f;
  for (int i = s0 + lane; i < s1; i += 64) den += __expf(elog[i] - m);
#pragma unroll
  for (int o = 1; o < 64; o <<= 1) den += __shfl_xor(den, o, 64);
  float rd = 1.f / den;
  float acc = __expf(sl - m) * h2[(size_t)node * 64 + lane];
  // ---- phase 2 ----
  if (nit > 0) {
    int nb = (nit + 7) >> 3;
    int laneE = lane & 7;
    int sv; float ev;
    {
      int i1 = min(s0 + laneE, s1 - 1);
      sv = pack[i1].y;
      ev = elog[i1];
    }
    float bufA[8], bufB[8];
#pragma unroll
    for (int j = 0; j < 8; ++j)
      bufA[j] = h2[(size_t)__shfl(sv, j, 64) * 64 + lane];
    for (int b = 0; b < nb; ++b) {
      int svN = 0; float evN = 0.f;
      bool pf = (b + 1 < nb);
      if (pf) {
        int i1 = min(s0 + (b + 1) * 8 + laneE, s1 - 1);
        svN = pack[i1].y;
        evN = elog[i1];
#pragma unroll
        for (int j = 0; j < 8; ++j)
          bufB[j] = h2[(size_t)__shfl(svN, j, 64) * 64 + lane];
      }
      int rem = nit - b * 8;
#pragma unroll
      for (int j = 0; j < 8; ++j) {
        float aj = __shfl(ev, j, 64);
        float ex = (j < rem) ? __expf(aj - m) : 0.f;
        acc = fmaf(ex, bufA[j], acc);
      }
      if (pf) {
#pragma unroll
        for (int j = 0; j < 8; ++j) bufA[j] = bufB[j];
        sv = svN; ev = evN;
      }
    }
  }
  out2[(size_t)node * 64 + lane] = acc * rd + b2[lane];  // H2=1: mean = identity
}

// ---------- pooling: sorted batch, wave handles 64 consecutive nodes ----------
__global__ __launch_bounds__(256) void k_pool(const float* __restrict__ out2,
                                              const int* __restrict__ batch,
                                              float* __restrict__ pooled,
                                              float* __restrict__ cnt, int n) {
  int wgl = blockIdx.x * 4 + (threadIdx.x >> 6);
  int lane = threadIdx.x & 63;
  int i0 = wgl * 64;
  if (i0 >= n) return;
  int i1 = min(i0 + 64, n);
  int cur = -1;
  float acc = 0.f, c = 0.f;
  for (int i = i0; i < i1; ++i) {
    int g = batch[i];
    if (g != cur) {
      if (cur >= 0) {
        atomicAdd(&pooled[cur * 64 + lane], acc);
        if (lane == 0) atomicAdd(&cnt[cur], c);
      }
      cur = g; acc = 0.f; c = 0.f;
    }
    acc += out2[(size_t)i * 64 + lane];
    c += 1.f;
  }
  if (cur >= 0) {
    atomicAdd(&pooled[cur * 64 + lane], acc);
    if (lane == 0) atomicAdd(&cnt[cur], c);
  }
}

// ---------- final: out[g,:] = (pooled[g,:]/cnt[g]) @ Pw + Pb ----------
__global__ __launch_bounds__(64) void k_final(const float* __restrict__ pooled,
                                              const float* __restrict__ cnt,
                                              const float* __restrict__ Pw,
                                              const float* __restrict__ Pb,
                                              float* __restrict__ out) {
  __shared__ float m[64];
  int g = blockIdx.x, o = threadIdx.x;
  m[o] = pooled[g * 64 + o] / fmaxf(cnt[g], 1.f);
  __syncthreads();
  float s = Pb[o];
#pragma unroll
  for (int c = 0; c < 64; ++c) s = fmaf(m[c], Pw[c * 64 + o], s);
  out[g * 64 + o] = s;
}

extern "C" void kernel_launch(void* const* d_in, const int* in_sizes, int n_in,
                              void* d_out, int out_size, void* d_ws, size_t ws_size,
                              hipStream_t stream) {
  const float* x         = (const float*)d_in[0];
  const int*   edge_index= (const int*)d_in[1];
  const float* edge_attr = (const float*)d_in[2];
  const int*   batch     = (const int*)d_in[3];
  const float* W1  = (const float*)d_in[4];
  const float* as1 = (const float*)d_in[5];
  const float* ad1 = (const float*)d_in[6];
  const float* We1 = (const float*)d_in[7];
  const float* ae1 = (const float*)d_in[8];
  const float* b1  = (const float*)d_in[9];
  const float* W2  = (const float*)d_in[10];
  const float* as2 = (const float*)d_in[11];
  const float* ad2 = (const float*)d_in[12];
  const float* We2 = (const float*)d_in[13];
  const float* ae2 = (const float*)d_in[14];
  const float* b2  = (const float*)d_in[15];
  const float* Pw  = (const float*)d_in[16];
  const float* Pb  = (const float*)d_in[17];

  const int N = in_sizes[0] / 128;
  const int E = in_sizes[1] / 2;
  const int G = out_size / 64;
  const int* srcI = edge_index;
  const int* dstI = edge_index + E;

  // ---- workspace layout (16B-aligned slots) ----
  float* ws = (float*)d_ws;
  size_t off = 0;
  auto alloc = [&](size_t elems) {
    float* p = ws + off;
    off += (elems + 3) & ~(size_t)3;
    return p;
  };
  int*   deg       = (int*)alloc(N);            // zeroed
  float* cnt       = alloc(G);                  // zeroed
  float* pooled    = alloc((size_t)G * 64);     // zeroed
  size_t zero_bytes = off * sizeof(float);
  int*   csr_off   = (int*)alloc(N + 1);
  int*   fill      = (int*)alloc(N);
  int*   bsum      = (int*)alloc(1024);
  int2*  pack      = (int2*)alloc((size_t)E * 2);   // {edge, src} per CSR slot
  float* ed2csr    = alloc((size_t)E);
  float* loopdot2  = alloc((size_t)N);
  float* h         = alloc((size_t)N * 64);     // h1, reused as h2
  float* als       = alloc((size_t)N * 4);      // layer2 reuses first N
  float* ald       = alloc((size_t)N * 4);
  float* selfl     = alloc((size_t)N * 4);      // layer2 reuses first N
  float* elog      = alloc((size_t)E * 4);      // layer2 reuses first E
  float* outn      = alloc((size_t)N * 64);     // out1, reused as out2

  (void)ws_size; (void)n_in;
  hipMemsetAsync(d_ws, 0, zero_bytes, stream);

  const int ebl   = (E + 255) / 256;
  const int nb    = (N + 255) / 256;
  const int nbl4  = (N + 3) / 4;
  const int nbl16 = (N + 15) / 16;
  const int gemb  = (N + 63) / 64;
  const int sctb  = (E + 511) / 512;   // scatter: 2 edges/thread

  // CSR build (by dst)
  k_deg<<<ebl, 256, 0, stream>>>(dstI, deg, E);
  k_chunksum<<<nb, 256, 0, stream>>>(deg, bsum, N);
  k_bscan<<<1, 256, 0, stream>>>(bsum, nb, csr_off, N);
  k_chunkscan<<<nb, 256, 0, stream>>>(deg, bsum, csr_off, fill, N);

  // fused: gemm1 (layer-1 linear + att logits) || CSR scatter
  k_gs<<<gemb + sctb, 256, 0, stream>>>(x, W1, as1, ad1, h, als, ald, N, gemb,
                                        dstI, srcI, fill, pack, E);

  // layer 1
  k_csrlog<<<nbl16, 256, 0, stream>>>(csr_off, pack, edge_attr, We1, ae1, We2, ae2,
                                      als, ald, elog, selfl, ed2csr, loopdot2, N);
  k_agg1<<<nbl4, 256, 0, stream>>>(csr_off, pack, elog, selfl, h, b1, outn, N);

  // layer 2 (reuses h/als/ald/selfl/elog slots; out2 overwrites out1)
  k_gemm2<<<gemb, 256, 0, stream>>>(outn, W2, as2, ad2, h, als, ald, N);
  k_l2log<<<nbl4, 256, 0, stream>>>(csr_off, pack, ed2csr, loopdot2, als, ald,
                                    elog, selfl, N);
  k_agg2<<<nbl4, 256, 0, stream>>>(csr_off, pack, elog, selfl, h, b2, outn, N);

  // pool + project
  k_pool<<<((N + 63) / 64 + 3) / 4, 256, 0, stream>>>(outn, batch, pooled, cnt, N);
  k_final<<<G, 64, 0, stream>>>(pooled, cnt, Pw, Pb, (float*)d_out);
}

// Round 8
// 244.135 us; speedup vs baseline: 1.4761x; 1.1771x over previous
//
#include <hip/hip_runtime.h>

#define LRELU(a) ((a) > 0.f ? (a) : 0.2f * (a))

// ---------- block-wide inclusive scan helper (256 threads, 4 waves) ----------
__device__ __forceinline__ int blockScanIncl256(int v, int* wl) {
  int t = threadIdx.x, lane = t & 63, w = t >> 6;
  int x = v;
#pragma unroll
  for (int o = 1; o < 64; o <<= 1) {
    int tmp = __shfl_up(x, (unsigned)o, 64);
    if (lane >= o) x += tmp;
  }
  if (lane == 63) wl[w] = x;
  __syncthreads();
  if (t == 0) {
    int s = 0;
#pragma unroll
    for (int j = 0; j < 4; ++j) { int tv = wl[j]; wl[j] = s; s += tv; }
  }
  __syncthreads();
  return x + wl[w];
}

// ---------- CSR build ----------
__global__ __launch_bounds__(256) void k_deg(const int* __restrict__ dst,
                                             int* __restrict__ deg, int E) {
  int e = blockIdx.x * 256 + threadIdx.x;
  if (e < E) atomicAdd(&deg[dst[e]], 1);
}

__global__ __launch_bounds__(256) void k_chunksum(const int* __restrict__ deg,
                                                  int* __restrict__ bsum, int n) {
  __shared__ int wl[4];
  int i = blockIdx.x * 256 + threadIdx.x;
  int v = (i < n) ? deg[i] : 0;
#pragma unroll
  for (int o = 1; o < 64; o <<= 1) v += __shfl_xor(v, o, 64);
  int lane = threadIdx.x & 63, w = threadIdx.x >> 6;
  if (lane == 0) wl[w] = v;
  __syncthreads();
  if (threadIdx.x == 0) bsum[blockIdx.x] = wl[0] + wl[1] + wl[2] + wl[3];
}

// single block; requires nb <= 256 (N <= 65536)
__global__ __launch_bounds__(256) void k_bscan(int* __restrict__ bsum, int nb,
                                               int* __restrict__ csr_off, int n) {
  __shared__ int wl[4];
  int t = threadIdx.x;
  int v = (t < nb) ? bsum[t] : 0;
  int incl = blockScanIncl256(v, wl);
  if (t < nb) bsum[t] = incl - v;  // exclusive block offsets
  if (t == 255) csr_off[n] = incl; // grand total
}

__global__ __launch_bounds__(256) void k_chunkscan(const int* __restrict__ deg,
                                                   const int* __restrict__ bsum,
                                                   int* __restrict__ csr_off,
                                                   int* __restrict__ fill, int n) {
  __shared__ int wl[4];
  int i = blockIdx.x * 256 + threadIdx.x;
  int v = (i < n) ? deg[i] : 0;
  int incl = blockScanIncl256(v, wl);
  int o = bsum[blockIdx.x] + incl - v;
  if (i < n) { csr_off[i] = o; fill[i] = o; }
}

// ---------- chunked-K tiled f32 GEMM body + fused attention-logit epilogue ----
// H[b0:b0+64][0:64] = X[b0:b0+64][0:K] @ W[K][64]; als/ald = h . a per head.
// 256 threads = 16x16, each computes a 4x4 tile. LDS ~17.5KB -> 8 blocks/CU.
template <int K, int HH>
__device__ __forceinline__ void gemm_body(const float* __restrict__ X,
                                          const float* __restrict__ W,
                                          const float* __restrict__ a_s,
                                          const float* __restrict__ a_d,
                                          float* __restrict__ H,
                                          float* __restrict__ als,
                                          float* __restrict__ ald,
                                          int n, int bid) {
  constexpr int KC = 32;
  __shared__ float Xs[64][KC + 4];   // 9216 B
  __shared__ float Ws[KC][64 + 4];   // 8704 B
  int t = threadIdx.x;
  int b0 = bid * 64;
  int tx = t & 15, ty = t >> 4;
  float acc[4][4] = {};
  for (int kc = 0; kc < K; kc += KC) {
    if (kc) __syncthreads();
    {
      int i = t * 8;
      int node = i >> 5, k = i & 31;
      int r = b0 + node;
      float4 v0 = make_float4(0.f, 0.f, 0.f, 0.f), v1 = v0;
      if (r < n) {
        const float* src = X + (size_t)r * K + kc + k;
        v0 = *(const float4*)src;
        v1 = *(const float4*)(src + 4);
      }
      *(float4*)&Xs[node][k] = v0;
      *(float4*)&Xs[node][k + 4] = v1;
    }
    {
      int i = t * 8;
      int kk = i >> 6, c = i & 63;
      const float* src = W + (size_t)(kc + kk) * 64 + c;
      *(float4*)&Ws[kk][c] = *(const float4*)src;
      *(float4*)&Ws[kk][c + 4] = *(const float4*)(src + 4);
    }
    __syncthreads();
#pragma unroll
    for (int k4 = 0; k4 < KC; k4 += 4) {
      float wvf[4][4];
#pragma unroll
      for (int j = 0; j < 4; ++j)
        *(float4*)&wvf[j][0] = *(const float4*)&Ws[k4 + j][tx * 4];
#pragma unroll
      for (int i = 0; i < 4; ++i) {
        float xvf[4];
        *(float4*)&xvf[0] = *(const float4*)&Xs[ty * 4 + i][k4];
#pragma unroll
        for (int kk = 0; kk < 4; ++kk)
#pragma unroll
          for (int j = 0; j < 4; ++j)
            acc[i][j] = fmaf(xvf[kk], wvf[kk][j], acc[i][j]);
      }
    }
  }
#pragma unroll
  for (int i = 0; i < 4; ++i) {
    int node = b0 + ty * 4 + i;
    if (node < n)
      *(float4*)&H[(size_t)node * 64 + tx * 4] =
          make_float4(acc[i][0], acc[i][1], acc[i][2], acc[i][3]);
  }
  // ---- fused attention logits: als/ald[node*HH+head] ----
  constexpr int C = 64 / HH;     // channels per head
  constexpr int GL = C / 4;      // tx lanes per head group
  float asv[4], adv[4];
#pragma unroll
  for (int j = 0; j < 4; ++j) { asv[j] = a_s[tx * 4 + j]; adv[j] = a_d[tx * 4 + j]; }
#pragma unroll
  for (int i = 0; i < 4; ++i) {
    float ps = 0.f, pd = 0.f;
#pragma unroll
    for (int j = 0; j < 4; ++j) {
      ps = fmaf(acc[i][j], asv[j], ps);
      pd = fmaf(acc[i][j], adv[j], pd);
    }
#pragma unroll
    for (int o = 1; o < GL; o <<= 1) {
      ps += __shfl_xor(ps, o, 64);
      pd += __shfl_xor(pd, o, 64);
    }
    int node = b0 + ty * 4 + i;
    if (node < n && (tx & (GL - 1)) == 0) {
      int head = tx / GL;
      als[(size_t)node * HH + head] = ps;
      ald[(size_t)node * HH + head] = pd;
    }
  }
}

__global__ __launch_bounds__(256) void k_gemm2(const float* __restrict__ X,
                                               const float* __restrict__ W,
                                               const float* __restrict__ a_s,
                                               const float* __restrict__ a_d,
                                               float* __restrict__ H,
                                               float* __restrict__ als,
                                               float* __restrict__ ald, int n) {
  gemm_body<64, 1>(X, W, a_s, a_d, H, als, ald, n, blockIdx.x);
}

// ---------- fused: gemm1 (blocks < gemmBlocks) || scatter+edge-dots (the rest) ----
// scatter: edge-ordered coalesced edge_attr read, dots vs (We1@ae1),(We2@ae2),
// ONE 32B scattered struct per edge: epk[p*8] = {d0,d1,d2,d3,q,src,-,-}.
__global__ __launch_bounds__(256) void k_gs(const float* __restrict__ X,
                                            const float* __restrict__ W,
                                            const float* __restrict__ a_s,
                                            const float* __restrict__ a_d,
                                            float* __restrict__ H,
                                            float* __restrict__ als,
                                            float* __restrict__ ald, int n,
                                            int gemmBlocks,
                                            const int* __restrict__ dst,
                                            const int* __restrict__ src,
                                            const float* __restrict__ edge_attr,
                                            const float* __restrict__ We1,
                                            const float* __restrict__ ae1,
                                            const float* __restrict__ We2,
                                            const float* __restrict__ ae2,
                                            int* __restrict__ fill,
                                            float* __restrict__ epk, int E) {
  if ((int)blockIdx.x < gemmBlocks) {
    gemm_body<128, 4>(X, W, a_s, a_d, H, als, ald, n, blockIdx.x);
  } else {
    __shared__ float wa1s[64];  // [k*4+h]
    __shared__ float wa2s[16];
    int t = threadIdx.x;
    if (t < 64) {
      int k = t >> 2, hh = t & 3;
      float s = 0.f;
#pragma unroll
      for (int c = 0; c < 16; ++c)
        s = fmaf(We1[k * 64 + hh * 16 + c], ae1[hh * 16 + c], s);
      wa1s[t] = s;
    } else if (t < 80) {
      int k = t - 64;
      float s = 0.f;
#pragma unroll
      for (int c = 0; c < 64; ++c) s = fmaf(We2[k * 64 + c], ae2[c], s);
      wa2s[k] = s;
    }
    __syncthreads();
    int base = (blockIdx.x - gemmBlocks) * 512 + t;
#pragma unroll
    for (int r = 0; r < 2; ++r) {
      int e = base + r * 256;
      if (e < E) {
        int d = dst[e], s = src[e];
        const float4* ea = (const float4*)(edge_attr + (size_t)e * 16);
        float ev[16];
        *(float4*)&ev[0]  = ea[0];
        *(float4*)&ev[4]  = ea[1];
        *(float4*)&ev[8]  = ea[2];
        *(float4*)&ev[12] = ea[3];
        float d0 = 0.f, d1 = 0.f, d2 = 0.f, d3 = 0.f, q = 0.f;
#pragma unroll
        for (int k = 0; k < 16; ++k) {
          float4 w1 = *(const float4*)&wa1s[k * 4];
          d0 = fmaf(ev[k], w1.x, d0);
          d1 = fmaf(ev[k], w1.y, d1);
          d2 = fmaf(ev[k], w1.z, d2);
          d3 = fmaf(ev[k], w1.w, d3);
          q  = fmaf(ev[k], wa2s[k], q);
        }
        int p = atomicAdd(&fill[d], 1);
        float* o = epk + (size_t)p * 8;
        *(float4*)o = make_float4(d0, d1, d2, d3);
        *(float4*)(o + 4) = make_float4(q, __int_as_float(s), 0.f, 0.f);
      }
    }
  }
}

// ---------- layer 1 aggregation: logits on the fly from epk + als1 gathers ----
// phase 1: online softmax (per-lane running m/den) + Σd,Σq -> self-loop + loopdot2
// phase 2: batched (8-deep, double-buffered) h gathers, logits recomputed inline
__global__ __launch_bounds__(256) void k_agg1(const int* __restrict__ csr_off,
                                              const float* __restrict__ epk,
                                              const float* __restrict__ als1,
                                              const float* __restrict__ ald1,
                                              const float* __restrict__ h1,
                                              const float* __restrict__ b1,
                                              float* __restrict__ out1,
                                              float* __restrict__ loopdot2, int n) {
  int t = threadIdx.x, w = t >> 6, lane = t & 63;
  int node = blockIdx.x * 4 + w;
  if (node >= n) return;
  int s0 = csr_off[node], s1 = csr_off[node + 1];
  int nit = s1 - s0;
  int laneB = lane >> 2, laneH = lane & 3;
  float adv = ald1[(size_t)node * 4 + laneH];
  // ---- phase 1: online m/den + sums ----
  float m = -3e38f, den = 0.f, sumd = 0.f, sumq = 0.f;
  for (int i = s0 + laneB; i < s1; i += 16) {
    float d = epk[(size_t)i * 8 + laneH];
    int s = __float_as_int(epk[(size_t)i * 8 + 5]);
    float q = epk[(size_t)i * 8 + 4];
    float a = als1[(size_t)s * 4 + laneH] + adv + d;
    a = LRELU(a);
    float nm = fmaxf(m, a);
    den = den * __expf(m - nm) + __expf(a - nm);
    m = nm;
    sumd += d;
    if (laneH == 0) sumq += q;
  }
#pragma unroll
  for (int o = 4; o < 64; o <<= 1) {
    float om = __shfl_xor(m, o, 64);
    float od = __shfl_xor(den, o, 64);
    float nm = fmaxf(m, om);
    den = den * __expf(m - nm) + od * __expf(om - nm);
    m = nm;
    sumd += __shfl_xor(sumd, o, 64);
    sumq += __shfl_xor(sumq, o, 64);
  }
  float cd = fmaxf((float)nit, 1.f);
  float sl = als1[(size_t)node * 4 + laneH] + adv + sumd / cd;
  sl = LRELU(sl);
  {
    float nm = fmaxf(m, sl);
    den = den * __expf(m - nm) + __expf(sl - nm);
    m = nm;
  }
  if (lane == 0) loopdot2[node] = sumq / cd;
  int head = lane >> 4;  // head in channel layout
  float m_ch = __shfl(m, head, 64);
  float rd_ch = 1.f / __shfl(den, head, 64);
  float sl_ch = __shfl(sl, head, 64);
  float acc = __expf(sl_ch - m_ch) * h1[(size_t)node * 64 + lane];
  float adv_h = __shfl(adv, head, 64);  // ald for this lane's channel head
  // ---- phase 2 ----
  if (nit > 0) {
    int nb = (nit + 7) >> 3;
    int laneE = lane & 7, laneB8 = (lane >> 2) & 7;
    int sv; float ev;
    float bufA[8], bufB[8];
    {
      int i1 = min(s0 + laneE, s1 - 1);
      sv = __float_as_int(epk[(size_t)i1 * 8 + 5]);
      int i2 = min(s0 + laneB8, s1 - 1);
      float d = epk[(size_t)i2 * 8 + laneH];
      int se = __float_as_int(epk[(size_t)i2 * 8 + 5]);
      ev = als1[(size_t)se * 4 + laneH] + adv + d;
      ev = LRELU(ev);
    }
#pragma unroll
    for (int j = 0; j < 8; ++j)
      bufA[j] = h1[(size_t)__shfl(sv, j, 64) * 64 + lane];
    for (int b = 0; b < nb; ++b) {
      int svN = 0; float evN = 0.f;
      bool pf = (b + 1 < nb);
      if (pf) {
        int base = s0 + (b + 1) * 8;
        int i1 = min(base + laneE, s1 - 1);
        svN = __float_as_int(epk[(size_t)i1 * 8 + 5]);
        int i2 = min(base + laneB8, s1 - 1);
        float d = epk[(size_t)i2 * 8 + laneH];
        int se = __float_as_int(epk[(size_t)i2 * 8 + 5]);
        evN = als1[(size_t)se * 4 + laneH] + adv + d;
        evN = LRELU(evN);
#pragma unroll
        for (int j = 0; j < 8; ++j)
          bufB[j] = h1[(size_t)__shfl(svN, j, 64) * 64 + lane];
      }
      int rem = nit - b * 8;
#pragma unroll
      for (int j = 0; j < 8; ++j) {
        float aj = __shfl(ev, j * 4 + head, 64);
        float ex = (j < rem) ? __expf(aj - m_ch) : 0.f;
        acc = fmaf(ex, bufA[j], acc);
      }
      if (pf) {
#pragma unroll
        for (int j = 0; j < 8; ++j) bufA[j] = bufB[j];
        sv = svN; ev = evN;
      }
    }
  }
  float r = acc * rd_ch + b1[lane];
  out1[(size_t)node * 64 + lane] = r > 0.f ? r : expm1f(r);  // ELU fused
  (void)adv_h;
}

// ---------- layer 2 aggregation (scalar head): logits from epk.q + als2 ----------
__global__ __launch_bounds__(256) void k_agg2(const int* __restrict__ csr_off,
                                              const float* __restrict__ epk,
                                              const float* __restrict__ als2,
                                              const float* __restrict__ ald2,
                                              const float* __restrict__ loopdot2,
                                              const float* __restrict__ h2,
                                              const float* __restrict__ b2,
                                              float* __restrict__ out2, int n) {
  int t = threadIdx.x, w = t >> 6, lane = t & 63;
  int node = blockIdx.x * 4 + w;
  if (node >= n) return;
  int s0 = csr_off[node], s1 = csr_off[node + 1];
  int nit = s1 - s0;
  float adv = ald2[node];
  // ---- phase 1: online m/den ----
  float m = -3e38f, den = 0.f;
  for (int i = s0 + lane; i < s1; i += 64) {
    float q = epk[(size_t)i * 8 + 4];
    int s = __float_as_int(epk[(size_t)i * 8 + 5]);
    float a = als2[s] + adv + q;
    a = LRELU(a);
    float nm = fmaxf(m, a);
    den = den * __expf(m - nm) + __expf(a - nm);
    m = nm;
  }
#pragma unroll
  for (int o = 1; o < 64; o <<= 1) {
    float om = __shfl_xor(m, o, 64);
    float od = __shfl_xor(den, o, 64);
    float nm = fmaxf(m, om);
    den = den * __expf(m - nm) + od * __expf(om - nm);
    m = nm;
  }
  float sl = als2[node] + adv + loopdot2[node];
  sl = LRELU(sl);
  {
    float nm = fmaxf(m, sl);
    den = den * __expf(m - nm) + __expf(sl - nm);
    m = nm;
  }
  float rd = 1.f / den;
  float acc = __expf(sl - m) * h2[(size_t)node * 64 + lane];
  // ---- phase 2 ----
  if (nit > 0) {
    int nb = (nit + 7) >> 3;
    int laneE = lane & 7;
    int sv; float ev;
    {
      int i1 = min(s0 + laneE, s1 - 1);
      float q = epk[(size_t)i1 * 8 + 4];
      sv = __float_as_int(epk[(size_t)i1 * 8 + 5]);
      ev = LRELU(als2[sv] + adv + q);
    }
    float bufA[8], bufB[8];
#pragma unroll
    for (int j = 0; j < 8; ++j)
      bufA[j] = h2[(size_t)__shfl(sv, j, 64) * 64 + lane];
    for (int b = 0; b < nb; ++b) {
      int svN = 0; float evN = 0.f;
      bool pf = (b + 1 < nb);
      if (pf) {
        int i1 = min(s0 + (b + 1) * 8 + laneE, s1 - 1);
        float q = epk[(size_t)i1 * 8 + 4];
        svN = __float_as_int(epk[(size_t)i1 * 8 + 5]);
        evN = LRELU(als2[svN] + adv + q);
#pragma unroll
        for (int j = 0; j < 8; ++j)
          bufB[j] = h2[(size_t)__shfl(svN, j, 64) * 64 + lane];
      }
      int rem = nit - b * 8;
#pragma unroll
      for (int j = 0; j < 8; ++j) {
        float aj = __shfl(ev, j, 64);
        float ex = (j < rem) ? __expf(aj - m) : 0.f;
        acc = fmaf(ex, bufA[j], acc);
      }
      if (pf) {
#pragma unroll
        for (int j = 0; j < 8; ++j) bufA[j] = bufB[j];
        sv = svN; ev = evN;
      }
    }
  }
  out2[(size_t)node * 64 + lane] = acc * rd + b2[lane];  // H2=1: mean = identity
}

// ---------- pooling: sorted batch, wave handles 64 consecutive nodes ----------
__global__ __launch_bounds__(256) void k_pool(const float* __restrict__ out2,
                                              const int* __restrict__ batch,
                                              float* __restrict__ pooled,
                                              float* __restrict__ cnt, int n) {
  int wgl = blockIdx.x * 4 + (threadIdx.x >> 6);
  int lane = threadIdx.x & 63;
  int i0 = wgl * 64;
  if (i0 >= n) return;
  int i1 = min(i0 + 64, n);
  int cur = -1;
  float acc = 0.f, c = 0.f;
  for (int i = i0; i < i1; ++i) {
    int g = batch[i];
    if (g != cur) {
      if (cur >= 0) {
        atomicAdd(&pooled[cur * 64 + lane], acc);
        if (lane == 0) atomicAdd(&cnt[cur], c);
      }
      cur = g; acc = 0.f; c = 0.f;
    }
    acc += out2[(size_t)i * 64 + lane];
    c += 1.f;
  }
  if (cur >= 0) {
    atomicAdd(&pooled[cur * 64 + lane], acc);
    if (lane == 0) atomicAdd(&cnt[cur], c);
  }
}

// ---------- final: out[g,:] = (pooled[g,:]/cnt[g]) @ Pw + Pb ----------
__global__ __launch_bounds__(64) void k_final(const float* __restrict__ pooled,
                                              const float* __restrict__ cnt,
                                              const float* __restrict__ Pw,
                                              const float* __restrict__ Pb,
                                              float* __restrict__ out) {
  __shared__ float m[64];
  int g = blockIdx.x, o = threadIdx.x;
  m[o] = pooled[g * 64 + o] / fmaxf(cnt[g], 1.f);
  __syncthreads();
  float s = Pb[o];
#pragma unroll
  for (int c = 0; c < 64; ++c) s = fmaf(m[c], Pw[c * 64 + o], s);
  out[g * 64 + o] = s;
}

extern "C" void kernel_launch(void* const* d_in, const int* in_sizes, int n_in,
                              void* d_out, int out_size, void* d_ws, size_t ws_size,
                              hipStream_t stream) {
  const float* x         = (const float*)d_in[0];
  const int*   edge_index= (const int*)d_in[1];
  const float* edge_attr = (const float*)d_in[2];
  const int*   batch     = (const int*)d_in[3];
  const float* W1  = (const float*)d_in[4];
  const float* as1 = (const float*)d_in[5];
  const float* ad1 = (const float*)d_in[6];
  const float* We1 = (const float*)d_in[7];
  const float* ae1 = (const float*)d_in[8];
  const float* b1  = (const float*)d_in[9];
  const float* W2  = (const float*)d_in[10];
  const float* as2 = (const float*)d_in[11];
  const float* ad2 = (const float*)d_in[12];
  const float* We2 = (const float*)d_in[13];
  const float* ae2 = (const float*)d_in[14];
  const float* b2  = (const float*)d_in[15];
  const float* Pw  = (const float*)d_in[16];
  const float* Pb  = (const float*)d_in[17];

  const int N = in_sizes[0] / 128;
  const int E = in_sizes[1] / 2;
  const int G = out_size / 64;
  const int* srcI = edge_index;
  const int* dstI = edge_index + E;

  // ---- workspace layout (32B-aligned slots) ----
  float* ws = (float*)d_ws;
  size_t off = 0;
  auto alloc = [&](size_t elems) {
    float* p = ws + off;
    off += (elems + 7) & ~(size_t)7;
    return p;
  };
  int*   deg       = (int*)alloc(N);            // zeroed
  float* cnt       = alloc(G);                  // zeroed
  float* pooled    = alloc((size_t)G * 64);     // zeroed
  size_t zero_bytes = off * sizeof(float);
  int*   csr_off   = (int*)alloc(N + 1);
  int*   fill      = (int*)alloc(N);
  int*   bsum      = (int*)alloc(1024);
  float* epk       = alloc((size_t)E * 8);      // {d0,d1,d2,d3,q,src,-,-}/CSR slot
  float* loopdot2  = alloc((size_t)N);
  float* h         = alloc((size_t)N * 64);     // h1, reused as h2
  float* als       = alloc((size_t)N * 4);      // layer2 reuses first N
  float* ald       = alloc((size_t)N * 4);
  float* outn      = alloc((size_t)N * 64);     // out1, reused as out2

  (void)ws_size; (void)n_in;
  hipMemsetAsync(d_ws, 0, zero_bytes, stream);

  const int ebl   = (E + 255) / 256;
  const int nb    = (N + 255) / 256;
  const int nbl4  = (N + 3) / 4;
  const int gemb  = (N + 63) / 64;
  const int sctb  = (E + 511) / 512;   // scatter: 2 edges/thread

  // CSR build (by dst)
  k_deg<<<ebl, 256, 0, stream>>>(dstI, deg, E);
  k_chunksum<<<nb, 256, 0, stream>>>(deg, bsum, N);
  k_bscan<<<1, 256, 0, stream>>>(bsum, nb, csr_off, N);
  k_chunkscan<<<nb, 256, 0, stream>>>(deg, bsum, csr_off, fill, N);

  // fused: gemm1 (layer-1 linear + att logits) || scatter + edge dots
  k_gs<<<gemb + sctb, 256, 0, stream>>>(x, W1, as1, ad1, h, als, ald, N, gemb,
                                        dstI, srcI, edge_attr, We1, ae1, We2, ae2,
                                        fill, epk, E);

  // layer 1 aggregation (also emits loopdot2 for layer 2)
  k_agg1<<<nbl4, 256, 0, stream>>>(csr_off, epk, als, ald, h, b1, outn, loopdot2, N);

  // layer 2
  k_gemm2<<<gemb, 256, 0, stream>>>(outn, W2, as2, ad2, h, als, ald, N);
  k_agg2<<<nbl4, 256, 0, stream>>>(csr_off, epk, als, ald, loopdot2, h, b2, outn, N);

  // pool + project
  k_pool<<<((N + 63) / 64 + 3) / 4, 256, 0, stream>>>(outn, batch, pooled, cnt, N);
  k_final<<<G, 64, 0, stream>>>(pooled, cnt, Pw, Pb, (float*)d_out);
}